// Round 14
// baseline (663.487 us; speedup 1.0000x reference)
//
#include <hip/hip_runtime.h>
#include <hip/hip_bf16.h>
#include <hip/hip_fp16.h>

#define NND 50000
#define NE  1600000
#define EMB 128
#define NH  8
#define HD  16
#define NB  98            // ceil(50000/512) buckets of 512 dst nodes

typedef __attribute__((ext_vector_type(8))) short short8v;
typedef __attribute__((ext_vector_type(4))) float f32x4;

__device__ __forceinline__ float lrelu(float x) { return x > 0.f ? x : 0.2f * x; }
__device__ __forceinline__ float elu(float x)   { return x > 0.f ? x : expm1f(x); }

__device__ __forceinline__ unsigned short f2bf(float x) {
    __hip_bfloat16 b = __float2bfloat16(x);
    return *reinterpret_cast<unsigned short*>(&b);
}
__device__ __forceinline__ float bf2f(unsigned short u) {
    __hip_bfloat16 b = *reinterpret_cast<__hip_bfloat16*>(&u);
    return __bfloat162float(b);
}

// ---------------- pack all 4 W matrices into per-fragment bf16 hi/lo ----------------
__global__ __launch_bounds__(256) void wpack4(
    const float* __restrict__ W, unsigned short* __restrict__ bphi, unsigned short* __restrict__ bplo)
{
    int s = blockIdx.x * 256 + threadIdx.x;   // grid 32 x 256 = 8192 = 4*2048
    int q    = s >> 11;
    int sidx = s & 2047;
    int n    = sidx >> 8;
    int kt   = (sidx >> 6) & 3;
    int lane = sidx & 63;
    int col  = n * 16 + (lane & 15);
    int krow = kt * 32 + ((lane >> 4) << 3);
    const float* Wm = W + (size_t)q * EMB * EMB;
    #pragma unroll
    for (int j = 0; j < 8; ++j) {
        float x = Wm[(size_t)(krow + j) * EMB + col];
        unsigned short hi = f2bf(x);
        unsigned short lo = f2bf(x - bf2f(hi));
        bphi[(size_t)s * 8 + j] = hi;
        bplo[(size_t)s * 8 + j] = lo;
    }
}

// ---------------- shared GEMM epilogue (feat now f16) ----------------
__device__ __forceinline__ void gemm_epilogue(
    f32x4 acc[2][2], int lane, int wave, int rowbase,
    const float* __restrict__ alv, const float* __restrict__ arv,
    unsigned short* __restrict__ feat_f16, float* __restrict__ el, float* __restrict__ er)
{
    const int colr = lane & 15;
    const int rgrp = lane >> 4;
    #pragma unroll
    for (int m = 0; m < 2; ++m) {
        const int row0 = rowbase + m * 16 + rgrp * 4;
        #pragma unroll
        for (int q = 0; q < 2; ++q) {
            const int nn = wave * 2 + q;
            f32x4 a = acc[m][q];
            #pragma unroll
            for (int r = 0; r < 4; ++r) {
                if (row0 + r < NND)
                    feat_f16[(size_t)(row0 + r) * EMB + nn * 16 + colr] =
                        __half_as_ushort(__float2half(a[r]));
            }
            const float alc = alv[nn * 16 + colr];
            const float arc = arv[nn * 16 + colr];
            float pl[4], pr[4];
            #pragma unroll
            for (int r = 0; r < 4; ++r) { pl[r] = a[r] * alc; pr[r] = a[r] * arc; }
            #pragma unroll
            for (int mask = 1; mask < 16; mask <<= 1) {
                #pragma unroll
                for (int r = 0; r < 4; ++r) {
                    pl[r] += __shfl_xor(pl[r], mask);
                    pr[r] += __shfl_xor(pr[r], mask);
                }
            }
            if (colr == 0) {
                #pragma unroll
                for (int r = 0; r < 4; ++r) {
                    int row = row0 + r;
                    if (row < NND) {
                        el[row * NH + nn] = pl[r];
                        er[row * NH + nn] = pr[r];
                    }
                }
            }
        }
    }
}

// ---------------- MFMA GEMM layer-1 (both paths): A = f32 fs, split in-register ----------------
__global__ __launch_bounds__(256) void mfma_gemm_f32(
    const float* __restrict__ fs,
    const unsigned short* __restrict__ bphi_all, const unsigned short* __restrict__ bplo_all,
    const float* __restrict__ al_all, const float* __restrict__ ar_all,
    unsigned short* __restrict__ feat_all, float* __restrict__ el_all, float* __restrict__ er_all)
{
    const int p = blockIdx.y;
    const int q4 = p * 2;                    // layer 0 of path p
    const float* hin = fs + (size_t)p * NND * EMB;
    const unsigned short* bphi = bphi_all + (size_t)q4 * 16384;
    const unsigned short* bplo = bplo_all + (size_t)q4 * 16384;
    const float* alv = al_all + (size_t)q4 * NH * HD;
    const float* arv = ar_all + (size_t)q4 * NH * HD;
    unsigned short* feat_f16 = feat_all + (size_t)p * NND * EMB;
    float* el = el_all + (size_t)p * NND * NH;
    float* er = er_all + (size_t)p * NND * NH;

    const int lane = threadIdx.x & 63;
    const int wave = threadIdx.x >> 6;
    const int rowbase = blockIdx.x * 32;

    f32x4 acc[2][2];
    #pragma unroll
    for (int m = 0; m < 2; ++m)
        #pragma unroll
        for (int q = 0; q < 2; ++q)
            acc[m][q] = (f32x4){0.f, 0.f, 0.f, 0.f};

    const int ar0 = rowbase + (lane & 15);
    const int ar1 = ar0 + 16;
    const int car0 = ar0 < NND ? ar0 : NND - 1;
    const int car1 = ar1 < NND ? ar1 : NND - 1;
    const int kofs = (lane >> 4) * 8;

    #pragma unroll
    for (int kt = 0; kt < 4; ++kt) {
        const int k0 = kt * 32 + kofs;
        short8v ah0, av0, ah1, av1;
        {
            const float4* fr = reinterpret_cast<const float4*>(hin + (size_t)car0 * EMB + k0);
            float4 x0 = fr[0], x1 = fr[1];
            float xs[8] = { x0.x, x0.y, x0.z, x0.w, x1.x, x1.y, x1.z, x1.w };
            #pragma unroll
            for (int j = 0; j < 8; ++j) {
                unsigned short hi = f2bf(xs[j]);
                ah0[j] = (short)hi;
                av0[j] = (short)f2bf(xs[j] - bf2f(hi));
            }
        }
        {
            const float4* fr = reinterpret_cast<const float4*>(hin + (size_t)car1 * EMB + k0);
            float4 x0 = fr[0], x1 = fr[1];
            float xs[8] = { x0.x, x0.y, x0.z, x0.w, x1.x, x1.y, x1.z, x1.w };
            #pragma unroll
            for (int j = 0; j < 8; ++j) {
                unsigned short hi = f2bf(xs[j]);
                ah1[j] = (short)hi;
                av1[j] = (short)f2bf(xs[j] - bf2f(hi));
            }
        }
        #pragma unroll
        for (int q = 0; q < 2; ++q) {
            const int nn = wave * 2 + q;
            const size_t bofs = ((size_t)(nn * 4 + kt) * 64 + lane) * 8;
            short8v bh = *reinterpret_cast<const short8v*>(bphi + bofs);
            short8v bl = *reinterpret_cast<const short8v*>(bplo + bofs);
            acc[0][q] = __builtin_amdgcn_mfma_f32_16x16x32_bf16(ah0, bh, acc[0][q], 0, 0, 0);
            acc[1][q] = __builtin_amdgcn_mfma_f32_16x16x32_bf16(ah1, bh, acc[1][q], 0, 0, 0);
            acc[0][q] = __builtin_amdgcn_mfma_f32_16x16x32_bf16(av0, bh, acc[0][q], 0, 0, 0);
            acc[1][q] = __builtin_amdgcn_mfma_f32_16x16x32_bf16(av1, bh, acc[1][q], 0, 0, 0);
            acc[0][q] = __builtin_amdgcn_mfma_f32_16x16x32_bf16(ah0, bl, acc[0][q], 0, 0, 0);
            acc[1][q] = __builtin_amdgcn_mfma_f32_16x16x32_bf16(ah1, bl, acc[1][q], 0, 0, 0);
        }
    }
    gemm_epilogue(acc, lane, wave, rowbase, alv, arv, feat_f16, el, er);
}

// ---------------- MFMA GEMM layer-2 (both paths): A = bf16 hi/lo ----------------
__global__ __launch_bounds__(256) void mfma_gemm_bf(
    const unsigned short* __restrict__ hhi_all, const unsigned short* __restrict__ hlo_all,
    const unsigned short* __restrict__ bphi_all, const unsigned short* __restrict__ bplo_all,
    const float* __restrict__ al_all, const float* __restrict__ ar_all,
    unsigned short* __restrict__ feat_all, float* __restrict__ el_all, float* __restrict__ er_all)
{
    const int p = blockIdx.y;
    const int q4 = p * 2 + 1;                // layer 1 of path p
    const unsigned short* hhi = hhi_all + (size_t)p * NND * EMB;
    const unsigned short* hlo = hlo_all + (size_t)p * NND * EMB;
    const unsigned short* bphi = bphi_all + (size_t)q4 * 16384;
    const unsigned short* bplo = bplo_all + (size_t)q4 * 16384;
    const float* alv = al_all + (size_t)q4 * NH * HD;
    const float* arv = ar_all + (size_t)q4 * NH * HD;
    unsigned short* feat_f16 = feat_all + (size_t)p * NND * EMB;
    float* el = el_all + (size_t)p * NND * NH;
    float* er = er_all + (size_t)p * NND * NH;

    const int lane = threadIdx.x & 63;
    const int wave = threadIdx.x >> 6;
    const int rowbase = blockIdx.x * 32;

    f32x4 acc[2][2];
    #pragma unroll
    for (int m = 0; m < 2; ++m)
        #pragma unroll
        for (int q = 0; q < 2; ++q)
            acc[m][q] = (f32x4){0.f, 0.f, 0.f, 0.f};

    const int ar0 = rowbase + (lane & 15);
    const int ar1 = ar0 + 16;
    const int car0 = ar0 < NND ? ar0 : NND - 1;
    const int car1 = ar1 < NND ? ar1 : NND - 1;
    const int kofs = (lane >> 4) * 8;

    #pragma unroll
    for (int kt = 0; kt < 4; ++kt) {
        const int k0 = kt * 32 + kofs;
        short8v ah0 = *reinterpret_cast<const short8v*>(hhi + (size_t)car0 * EMB + k0);
        short8v av0 = *reinterpret_cast<const short8v*>(hlo + (size_t)car0 * EMB + k0);
        short8v ah1 = *reinterpret_cast<const short8v*>(hhi + (size_t)car1 * EMB + k0);
        short8v av1 = *reinterpret_cast<const short8v*>(hlo + (size_t)car1 * EMB + k0);
        #pragma unroll
        for (int q = 0; q < 2; ++q) {
            const int nn = wave * 2 + q;
            const size_t bofs = ((size_t)(nn * 4 + kt) * 64 + lane) * 8;
            short8v bh = *reinterpret_cast<const short8v*>(bphi + bofs);
            short8v bl = *reinterpret_cast<const short8v*>(bplo + bofs);
            acc[0][q] = __builtin_amdgcn_mfma_f32_16x16x32_bf16(ah0, bh, acc[0][q], 0, 0, 0);
            acc[1][q] = __builtin_amdgcn_mfma_f32_16x16x32_bf16(ah1, bh, acc[1][q], 0, 0, 0);
            acc[0][q] = __builtin_amdgcn_mfma_f32_16x16x32_bf16(av0, bh, acc[0][q], 0, 0, 0);
            acc[1][q] = __builtin_amdgcn_mfma_f32_16x16x32_bf16(av1, bh, acc[1][q], 0, 0, 0);
            acc[0][q] = __builtin_amdgcn_mfma_f32_16x16x32_bf16(ah0, bl, acc[0][q], 0, 0, 0);
            acc[1][q] = __builtin_amdgcn_mfma_f32_16x16x32_bf16(ah1, bl, acc[1][q], 0, 0, 0);
        }
    }
    gemm_epilogue(acc, lane, wave, rowbase, alv, arv, feat_f16, el, er);
}

// ---------------- CSR build: both paths (blockIdx.y = path) ----------------
__global__ __launch_bounds__(256) void bucket_count(
    const int* __restrict__ edges, int* __restrict__ bcnt)
{
    const int p = blockIdx.y;
    const int* dst = edges + (size_t)p * 2 * NE + NE;
    __shared__ int hist[NB];
    const int t = threadIdx.x;
    for (int b = t; b < NB; b += 256) hist[b] = 0;
    __syncthreads();
    const int e0 = blockIdx.x * 2048 + t * 8;
    #pragma unroll
    for (int j = 0; j < 8; ++j) {
        int e = e0 + j;
        if (e < NE) atomicAdd(&hist[dst[e] >> 9], 1);
    }
    __syncthreads();
    for (int b = t; b < NB; b += 256)
        if (hist[b]) atomicAdd(&bcnt[p * 128 + b], hist[b]);
}

__global__ __launch_bounds__(128) void scan_bucket(
    const int* __restrict__ bcnt, int* __restrict__ bbase, int* __restrict__ bcur)
{
    const int p = blockIdx.x;
    __shared__ int s[128];
    const int t = threadIdx.x;
    s[t] = (t < NB) ? bcnt[p * 128 + t] : 0;
    __syncthreads();
    for (int off = 1; off < 128; off <<= 1) {
        int v = (t >= off) ? s[t - off] : 0;
        __syncthreads();
        s[t] += v;
        __syncthreads();
    }
    int excl = (t > 0) ? s[t - 1] : 0;
    if (t <= NB) bbase[p * 128 + t] = excl;
    if (t < NB)  bcur[p * 128 + t]  = excl;
}

__global__ __launch_bounds__(256) void bucket_scatter(
    const int* __restrict__ edges, int* __restrict__ bcur, int* __restrict__ ebuf)
{
    const int p = blockIdx.y;
    const int* src = edges + (size_t)p * 2 * NE;
    const int* dst = src + NE;
    int* eb = ebuf + (size_t)p * NE;
    __shared__ int hist[NB];
    __shared__ int base[NB];
    __shared__ int lcur[NB];
    const int t  = threadIdx.x;
    const int e0 = blockIdx.x * 2048 + t * 8;

    for (int b = t; b < NB; b += 256) { hist[b] = 0; lcur[b] = 0; }
    __syncthreads();

    int sj[8], dj[8];
    bool vj[8];
    #pragma unroll
    for (int j = 0; j < 8; ++j) {
        int e = e0 + j;
        vj[j] = (e < NE);
        if (vj[j]) {
            sj[j] = src[e];
            dj[j] = dst[e];
            atomicAdd(&hist[dj[j] >> 9], 1);
        }
    }
    __syncthreads();
    for (int b = t; b < NB; b += 256) {
        int c = hist[b];
        base[b] = c > 0 ? atomicAdd(&bcur[p * 128 + b], c) : 0;
    }
    __syncthreads();
    #pragma unroll
    for (int j = 0; j < 8; ++j) {
        if (vj[j]) {
            int b   = dj[j] >> 9;
            int off = atomicAdd(&lcur[b], 1);
            eb[(size_t)base[b] + off] = (sj[j] << 9) | (dj[j] & 511);
        }
    }
}

__global__ __launch_bounds__(1024) void bucket_fill(
    const int* __restrict__ bbase, const int* __restrict__ ebuf,
    int* __restrict__ rowptr, int* __restrict__ csrsrc)
{
    const int p = blockIdx.y;
    const int* eb = ebuf + (size_t)p * NE;
    int* rp = rowptr + (size_t)p * (NND + 1);
    int* cs = csrsrc + (size_t)p * NE;
    __shared__ int hist[512];
    __shared__ int excl[512];
    const int b    = blockIdx.x;
    const int n0   = b << 9;
    const int t    = threadIdx.x;
    const int base = bbase[p * 128 + b];
    const int cnt  = bbase[p * 128 + b + 1] - base;

    if (t < 512) hist[t] = 0;
    __syncthreads();
    for (int i = t; i < cnt; i += 1024)
        atomicAdd(&hist[eb[base + i] & 511], 1);
    __syncthreads();
    if (t < 512) excl[t] = hist[t];
    __syncthreads();
    for (int off = 1; off < 512; off <<= 1) {
        int v = 0;
        if (t < 512 && t >= off) v = excl[t - off];
        __syncthreads();
        if (t < 512) excl[t] += v;
        __syncthreads();
    }
    if (t < 512) {
        int e = excl[t] - hist[t];
        int n = n0 + t;
        if (n < NND) rp[n] = base + e;
        hist[t] = e;
    }
    if (b == NB - 1 && t == 0) rp[NND] = NE;
    __syncthreads();
    for (int i = t; i < cnt; i += 1024) {
        int ed = eb[base + i];
        int q = atomicAdd(&hist[ed & 511], 1);
        cs[base + q] = ed >> 9;
    }
}

// ---------------- wexp pass: w per CSR slot (f16) + esum; zero redundancy ----------------
__global__ __launch_bounds__(256) void wexp_pass(
    const int* __restrict__ rowptr_all, const int* __restrict__ csrsrc_all,
    const float* __restrict__ el_all, const float* __restrict__ er_all,
    unsigned short* __restrict__ wexp_all, float* __restrict__ esum_all)
{
    const int p    = blockIdx.y;
    const int wid  = (blockIdx.x * blockDim.x + threadIdx.x) >> 6;
    const int lane = threadIdx.x & 63;
    if (wid >= NND) return;
    const int n  = wid;
    const int h  = lane >> 3;
    const int j8 = lane & 7;

    const int* rowptr = rowptr_all + (size_t)p * (NND + 1);
    const int* csrsrc = csrsrc_all + (size_t)p * NE;
    const float* el   = el_all + (size_t)p * NND * NH;
    const float* er   = er_all + (size_t)p * NND * NH;
    unsigned short* wexp = wexp_all + (size_t)p * NE * NH;

    const float ern = er[n * NH + h];
    const int r0 = __builtin_amdgcn_readfirstlane(rowptr[n]);
    const int r1 = __builtin_amdgcn_readfirstlane(rowptr[n + 1]);

    float esp = 0.f;
    for (int i = r0; i < r1; i += 16) {
        int i0 = i + j8, i1 = i + j8 + 8;
        bool v0 = i0 < r1, v1 = i1 < r1;
        int s0 = csrsrc[v0 ? i0 : r0];
        int s1 = csrsrc[v1 ? i1 : r0];
        float w0 = __expf(lrelu(el[s0 * NH + h] + ern));
        float w1 = __expf(lrelu(el[s1 * NH + h] + ern));
        if (v0) { esp += w0; wexp[(size_t)i0 * NH + h] = __half_as_ushort(__float2half(w0)); }
        if (v1) { esp += w1; wexp[(size_t)i1 * NH + h] = __half_as_ushort(__float2half(w1)); }
    }
    esp += __shfl_xor(esp, 1);
    esp += __shfl_xor(esp, 2);
    esp += __shfl_xor(esp, 4);
    if (j8 == 0) esum_all[((size_t)p * NND + n) * NH + h] = esp;
}

// ---------------- Gather-aggregate (both paths): one wave per destination node ----------------
// No exp in the hot loop: w streamed as f16, feat as f16 pairs (v_fma_mix).
__global__ __launch_bounds__(256) void gather_agg(
    const int* __restrict__ rowptr_all, const int* __restrict__ csrsrc_all,
    const unsigned short* __restrict__ wexp_all, const float* __restrict__ esum_all,
    const unsigned int* __restrict__ feat_all,
    const float* __restrict__ fs,               // layer0 residual
    const unsigned int* __restrict__ hhi_all,   // l0: out; l1: residual
    const unsigned int* __restrict__ hlo_all,
    const float* __restrict__ bias_all,
    float* __restrict__ out_emb,                // layer1 out
    int layer)
{
    const int p    = blockIdx.y;
    const int wid  = (blockIdx.x * blockDim.x + threadIdx.x) >> 6;
    const int lane = threadIdx.x & 63;
    if (wid >= NND) return;
    const int n = wid;
    const int h = lane >> 3;

    const int* rowptr = rowptr_all + (size_t)p * (NND + 1);
    const int* csrsrc = csrsrc_all + (size_t)p * NE;
    const unsigned short* wexp = wexp_all + (size_t)p * NE * NH;
    const unsigned int* featu = feat_all + (size_t)p * NND * 64;
    const float* bias = bias_all + (size_t)(p * 2 + layer) * EMB;

    const int r0 = __builtin_amdgcn_readfirstlane(rowptr[n]);
    const int r1 = __builtin_amdgcn_readfirstlane(rowptr[n + 1]);

    float acc0 = 0.f, acc1 = 0.f;

    int i = r0;
    for (; i + 16 <= r1; i += 16) {
        int sj[16];
        #pragma unroll
        for (int j = 0; j < 16; ++j) sj[j] = csrsrc[i + j];          // uniform
        unsigned int vs[16];
        #pragma unroll
        for (int j = 0; j < 16; ++j) vs[j] = featu[(size_t)sj[j] * 64 + lane];
        unsigned short wu[16];
        #pragma unroll
        for (int j = 0; j < 16; ++j) wu[j] = wexp[(size_t)(i + j) * NH + h];
        #pragma unroll
        for (int j = 0; j < 16; ++j) {
            float w = __half2float(__ushort_as_half(wu[j]));
            __half2 v = *reinterpret_cast<__half2*>(&vs[j]);
            acc0 = fmaf(w, __half2float(__low2half(v)), acc0);
            acc1 = fmaf(w, __half2float(__high2half(v)), acc1);
        }
    }
    if (i + 8 <= r1) {
        int sj[8];
        #pragma unroll
        for (int j = 0; j < 8; ++j) sj[j] = csrsrc[i + j];
        unsigned int vs[8];
        #pragma unroll
        for (int j = 0; j < 8; ++j) vs[j] = featu[(size_t)sj[j] * 64 + lane];
        unsigned short wu[8];
        #pragma unroll
        for (int j = 0; j < 8; ++j) wu[j] = wexp[(size_t)(i + j) * NH + h];
        #pragma unroll
        for (int j = 0; j < 8; ++j) {
            float w = __half2float(__ushort_as_half(wu[j]));
            __half2 v = *reinterpret_cast<__half2*>(&vs[j]);
            acc0 = fmaf(w, __half2float(__low2half(v)), acc0);
            acc1 = fmaf(w, __half2float(__high2half(v)), acc1);
        }
        i += 8;
    }
    for (; i < r1; ++i) {
        int sj = csrsrc[i];
        unsigned int vraw = featu[(size_t)sj * 64 + lane];
        float w = __half2float(__ushort_as_half(wexp[(size_t)i * NH + h]));
        __half2 v = *reinterpret_cast<__half2*>(&vraw);
        acc0 = fmaf(w, __half2float(__low2half(v)), acc0);
        acc1 = fmaf(w, __half2float(__high2half(v)), acc1);
    }

    const float es  = esum_all[((size_t)p * NND + n) * NH + h];
    const float inv = 1.f / fmaxf(es, 1e-9f);

    float h0, h1;
    if (layer == 0) {
        float2 hv = reinterpret_cast<const float2*>(fs + (size_t)p * NND * EMB)[(size_t)n * 64 + lane];
        h0 = hv.x; h1 = hv.y;
    } else {
        unsigned int hiu = hhi_all[((size_t)p * NND + n) * 64 + lane];
        unsigned int lou = hlo_all[((size_t)p * NND + n) * 64 + lane];
        h0 = __uint_as_float(hiu << 16) + __uint_as_float(lou << 16);
        h1 = __uint_as_float(hiu & 0xffff0000u) + __uint_as_float(lou & 0xffff0000u);
    }
    float o0 = elu(fmaf(acc0, inv, h0 + bias[lane * 2]));
    float o1 = elu(fmaf(acc1, inv, h1 + bias[lane * 2 + 1]));

    if (layer == 1) {
        reinterpret_cast<float2*>(out_emb + (size_t)p * NND * EMB)[(size_t)n * 64 + lane] =
            make_float2(o0, o1);
    } else {
        unsigned short hi0 = f2bf(o0), hi1 = f2bf(o1);
        unsigned short lo0 = f2bf(o0 - bf2f(hi0)), lo1 = f2bf(o1 - bf2f(hi1));
        const size_t idx = ((size_t)p * NND + n) * 64 + lane;
        const_cast<unsigned int*>(hhi_all)[idx] = (unsigned int)hi0 | ((unsigned int)hi1 << 16);
        const_cast<unsigned int*>(hlo_all)[idx] = (unsigned int)lo0 | ((unsigned int)lo1 << 16);
    }
}

// ---------------- alpha (both paths): one thread per edge, all 8 heads ----------------
__global__ __launch_bounds__(256) void alpha_write8(
    const int* __restrict__ edges,
    const float* __restrict__ el_all, const float* __restrict__ er_all,
    const float* __restrict__ esum_all, float* __restrict__ out_alpha)
{
    const int p = blockIdx.y;
    int e = blockIdx.x * 256 + threadIdx.x;
    if (e >= NE) return;
    const int* src = edges + (size_t)p * 2 * NE;
    const int* dst = src + NE;
    const float* el   = el_all   + (size_t)p * NND * NH;
    const float* er   = er_all   + (size_t)p * NND * NH;
    const float* esum = esum_all + (size_t)p * NND * NH;
    int s = src[e], d = dst[e];
    const float4* el4 = reinterpret_cast<const float4*>(el + (size_t)s * 8);
    const float4* er4 = reinterpret_cast<const float4*>(er + (size_t)d * 8);
    const float4* es4 = reinterpret_cast<const float4*>(esum + (size_t)d * 8);
    float4 L0 = el4[0], L1 = el4[1];
    float4 R0 = er4[0], R1 = er4[1];
    float4 S0 = es4[0], S1 = es4[1];
    float4 a0, a1;
    a0.x = __fdividef(__expf(lrelu(L0.x + R0.x)), fmaxf(S0.x, 1e-9f));
    a0.y = __fdividef(__expf(lrelu(L0.y + R0.y)), fmaxf(S0.y, 1e-9f));
    a0.z = __fdividef(__expf(lrelu(L0.z + R0.z)), fmaxf(S0.z, 1e-9f));
    a0.w = __fdividef(__expf(lrelu(L0.w + R0.w)), fmaxf(S0.w, 1e-9f));
    a1.x = __fdividef(__expf(lrelu(L1.x + R1.x)), fmaxf(S1.x, 1e-9f));
    a1.y = __fdividef(__expf(lrelu(L1.y + R1.y)), fmaxf(S1.y, 1e-9f));
    a1.z = __fdividef(__expf(lrelu(L1.z + R1.z)), fmaxf(S1.z, 1e-9f));
    a1.w = __fdividef(__expf(lrelu(L1.w + R1.w)), fmaxf(S1.w, 1e-9f));
    float4* o4 = reinterpret_cast<float4*>(out_alpha + ((size_t)p * NE + e) * 8);
    o4[0] = a0;
    o4[1] = a1;
}

extern "C" void kernel_launch(void* const* d_in, const int* in_sizes, int n_in,
                              void* d_out, int out_size, void* d_ws, size_t ws_size,
                              hipStream_t stream) {
    const float* fs   = (const float*)d_in[0];  // [2][N][128]
    const float* W    = (const float*)d_in[1];  // [2][2][128][128]
    const float* al   = (const float*)d_in[2];  // [2][2][8][16]
    const float* ar   = (const float*)d_in[3];  // [2][2][8][16]
    const float* bias = (const float*)d_in[4];  // [2][2][128]
    const int*   edges= (const int*)d_in[5];    // [2][2][E]

    float* out       = (float*)d_out;
    float* out_emb   = out;                              // [2][N][128]
    float* out_alpha = out + (size_t)2 * NND * EMB;      // [2][E][8]

    char* ws = (char*)d_ws;
    auto take = [&](size_t bytes) {
        char* r = ws;
        ws += (bytes + 15) & ~(size_t)15;
        return r;
    };
    unsigned short* feat_f16 = (unsigned short*)take((size_t)2 * NND * EMB * 2);  // [2][N][128] f16
    unsigned short* hhi      = (unsigned short*)take((size_t)2 * NND * EMB * 2);
    unsigned short* hlo      = (unsigned short*)take((size_t)2 * NND * EMB * 2);  // ebuf aliases here
    float*          el       = (float*)take((size_t)2 * NND * NH * 4);
    float*          er       = (float*)take((size_t)2 * NND * NH * 4);
    float*          esum     = (float*)take((size_t)2 * NND * NH * 4);
    int*            rowptr   = (int*)take((size_t)2 * (NND + 1) * 4);
    int*            bcnt     = (int*)take((size_t)2 * 128 * 4);
    int*            bbase    = (int*)take((size_t)2 * 128 * 4);
    int*            bcur     = (int*)take((size_t)2 * 128 * 4);
    int*            csrsrc   = (int*)take((size_t)2 * NE * 4);
    unsigned short* wexp     = (unsigned short*)take((size_t)2 * NE * NH * 2);    // [2][NE][8] f16
    unsigned short* bphi     = (unsigned short*)take((size_t)4 * 16384 * 2);
    unsigned short* bplo     = (unsigned short*)take((size_t)4 * 16384 * 2);

    int*          ebuf  = (int*)hlo;            // dead until gather l0 writes hlo
    unsigned int* featu = (unsigned int*)feat_f16;
    unsigned int* hhi_u = (unsigned int*)hhi;
    unsigned int* hlo_u = (unsigned int*)hlo;

    // --- CSR build, both paths ---
    hipMemsetAsync(bcnt, 0, (size_t)2 * 128 * 4, stream);
    bucket_count<<<dim3((NE + 2047) / 2048, 2), 256, 0, stream>>>(edges, bcnt);
    scan_bucket<<<2, 128, 0, stream>>>(bcnt, bbase, bcur);
    bucket_scatter<<<dim3((NE + 2047) / 2048, 2), 256, 0, stream>>>(edges, bcur, ebuf);
    bucket_fill<<<dim3(NB, 2), 1024, 0, stream>>>(bbase, ebuf, rowptr, csrsrc);

    // --- weights ---
    wpack4<<<32, 256, 0, stream>>>(W, bphi, bplo);

    // --- layer 0 (both paths per launch) ---
    mfma_gemm_f32<<<dim3((NND + 31) / 32, 2), 256, 0, stream>>>(
        fs, bphi, bplo, al, ar, feat_f16, el, er);
    wexp_pass<<<dim3((NND + 3) / 4, 2), 256, 0, stream>>>(
        rowptr, csrsrc, el, er, wexp, esum);
    gather_agg<<<dim3((NND + 3) / 4, 2), 256, 0, stream>>>(
        rowptr, csrsrc, wexp, esum, featu, fs, hhi_u, hlo_u, bias, nullptr, 0);

    // --- layer 1 (both paths per launch) ---
    mfma_gemm_bf<<<dim3((NND + 31) / 32, 2), 256, 0, stream>>>(
        hhi, hlo, bphi, bplo, al, ar, feat_f16, el, er);
    wexp_pass<<<dim3((NND + 3) / 4, 2), 256, 0, stream>>>(
        rowptr, csrsrc, el, er, wexp, esum);
    gather_agg<<<dim3((NND + 3) / 4, 2), 256, 0, stream>>>(
        rowptr, csrsrc, wexp, esum, featu, fs, hhi_u, hlo_u, bias, out_emb, 1);
    alpha_write8<<<dim3((NE + 255) / 256, 2), 256, 0, stream>>>(
        edges, el, er, esum, out_alpha);
}

// Round 15
// 619.952 us; speedup vs baseline: 1.0702x; 1.0702x over previous
//
#include <hip/hip_runtime.h>
#include <hip/hip_bf16.h>
#include <hip/hip_fp16.h>

#define NND 50000
#define NE  1600000
#define EMB 128
#define NH  8
#define HD  16
#define NB  98            // ceil(50000/512) buckets of 512 dst nodes

typedef __attribute__((ext_vector_type(8))) short short8v;
typedef __attribute__((ext_vector_type(4))) float f32x4;

__device__ __forceinline__ float lrelu(float x) { return x > 0.f ? x : 0.2f * x; }
__device__ __forceinline__ float elu(float x)   { return x > 0.f ? x : expm1f(x); }

__device__ __forceinline__ unsigned short f2bf(float x) {
    __hip_bfloat16 b = __float2bfloat16(x);
    return *reinterpret_cast<unsigned short*>(&b);
}
__device__ __forceinline__ float bf2f(unsigned short u) {
    __hip_bfloat16 b = *reinterpret_cast<__hip_bfloat16*>(&u);
    return __bfloat162float(b);
}

// ---------------- pack all 4 W matrices into per-fragment bf16 hi/lo ----------------
__global__ __launch_bounds__(256) void wpack4(
    const float* __restrict__ W, unsigned short* __restrict__ bphi, unsigned short* __restrict__ bplo)
{
    int s = blockIdx.x * 256 + threadIdx.x;   // grid 32 x 256 = 8192 = 4*2048
    int q    = s >> 11;
    int sidx = s & 2047;
    int n    = sidx >> 8;
    int kt   = (sidx >> 6) & 3;
    int lane = sidx & 63;
    int col  = n * 16 + (lane & 15);
    int krow = kt * 32 + ((lane >> 4) << 3);
    const float* Wm = W + (size_t)q * EMB * EMB;
    #pragma unroll
    for (int j = 0; j < 8; ++j) {
        float x = Wm[(size_t)(krow + j) * EMB + col];
        unsigned short hi = f2bf(x);
        unsigned short lo = f2bf(x - bf2f(hi));
        bphi[(size_t)s * 8 + j] = hi;
        bplo[(size_t)s * 8 + j] = lo;
    }
}

// ---------------- shared GEMM epilogue (feat f16) ----------------
__device__ __forceinline__ void gemm_epilogue(
    f32x4 acc[2][2], int lane, int wave, int rowbase,
    const float* __restrict__ alv, const float* __restrict__ arv,
    unsigned short* __restrict__ feat_f16, float* __restrict__ el, float* __restrict__ er)
{
    const int colr = lane & 15;
    const int rgrp = lane >> 4;
    #pragma unroll
    for (int m = 0; m < 2; ++m) {
        const int row0 = rowbase + m * 16 + rgrp * 4;
        #pragma unroll
        for (int q = 0; q < 2; ++q) {
            const int nn = wave * 2 + q;
            f32x4 a = acc[m][q];
            #pragma unroll
            for (int r = 0; r < 4; ++r) {
                if (row0 + r < NND)
                    feat_f16[(size_t)(row0 + r) * EMB + nn * 16 + colr] =
                        __half_as_ushort(__float2half(a[r]));
            }
            const float alc = alv[nn * 16 + colr];
            const float arc = arv[nn * 16 + colr];
            float pl[4], pr[4];
            #pragma unroll
            for (int r = 0; r < 4; ++r) { pl[r] = a[r] * alc; pr[r] = a[r] * arc; }
            #pragma unroll
            for (int mask = 1; mask < 16; mask <<= 1) {
                #pragma unroll
                for (int r = 0; r < 4; ++r) {
                    pl[r] += __shfl_xor(pl[r], mask);
                    pr[r] += __shfl_xor(pr[r], mask);
                }
            }
            if (colr == 0) {
                #pragma unroll
                for (int r = 0; r < 4; ++r) {
                    int row = row0 + r;
                    if (row < NND) {
                        el[row * NH + nn] = pl[r];
                        er[row * NH + nn] = pr[r];
                    }
                }
            }
        }
    }
}

// ---------------- MFMA GEMM layer-1 (both paths): A = f32 fs, split in-register ----------------
__global__ __launch_bounds__(256) void mfma_gemm_f32(
    const float* __restrict__ fs,
    const unsigned short* __restrict__ bphi_all, const unsigned short* __restrict__ bplo_all,
    const float* __restrict__ al_all, const float* __restrict__ ar_all,
    unsigned short* __restrict__ feat_all, float* __restrict__ el_all, float* __restrict__ er_all)
{
    const int p = blockIdx.y;
    const int q4 = p * 2;
    const float* hin = fs + (size_t)p * NND * EMB;
    const unsigned short* bphi = bphi_all + (size_t)q4 * 16384;
    const unsigned short* bplo = bplo_all + (size_t)q4 * 16384;
    const float* alv = al_all + (size_t)q4 * NH * HD;
    const float* arv = ar_all + (size_t)q4 * NH * HD;
    unsigned short* feat_f16 = feat_all + (size_t)p * NND * EMB;
    float* el = el_all + (size_t)p * NND * NH;
    float* er = er_all + (size_t)p * NND * NH;

    const int lane = threadIdx.x & 63;
    const int wave = threadIdx.x >> 6;
    const int rowbase = blockIdx.x * 32;

    f32x4 acc[2][2];
    #pragma unroll
    for (int m = 0; m < 2; ++m)
        #pragma unroll
        for (int q = 0; q < 2; ++q)
            acc[m][q] = (f32x4){0.f, 0.f, 0.f, 0.f};

    const int ar0 = rowbase + (lane & 15);
    const int ar1 = ar0 + 16;
    const int car0 = ar0 < NND ? ar0 : NND - 1;
    const int car1 = ar1 < NND ? ar1 : NND - 1;
    const int kofs = (lane >> 4) * 8;

    #pragma unroll
    for (int kt = 0; kt < 4; ++kt) {
        const int k0 = kt * 32 + kofs;
        short8v ah0, av0, ah1, av1;
        {
            const float4* fr = reinterpret_cast<const float4*>(hin + (size_t)car0 * EMB + k0);
            float4 x0 = fr[0], x1 = fr[1];
            float xs[8] = { x0.x, x0.y, x0.z, x0.w, x1.x, x1.y, x1.z, x1.w };
            #pragma unroll
            for (int j = 0; j < 8; ++j) {
                unsigned short hi = f2bf(xs[j]);
                ah0[j] = (short)hi;
                av0[j] = (short)f2bf(xs[j] - bf2f(hi));
            }
        }
        {
            const float4* fr = reinterpret_cast<const float4*>(hin + (size_t)car1 * EMB + k0);
            float4 x0 = fr[0], x1 = fr[1];
            float xs[8] = { x0.x, x0.y, x0.z, x0.w, x1.x, x1.y, x1.z, x1.w };
            #pragma unroll
            for (int j = 0; j < 8; ++j) {
                unsigned short hi = f2bf(xs[j]);
                ah1[j] = (short)hi;
                av1[j] = (short)f2bf(xs[j] - bf2f(hi));
            }
        }
        #pragma unroll
        for (int q = 0; q < 2; ++q) {
            const int nn = wave * 2 + q;
            const size_t bofs = ((size_t)(nn * 4 + kt) * 64 + lane) * 8;
            short8v bh = *reinterpret_cast<const short8v*>(bphi + bofs);
            short8v bl = *reinterpret_cast<const short8v*>(bplo + bofs);
            acc[0][q] = __builtin_amdgcn_mfma_f32_16x16x32_bf16(ah0, bh, acc[0][q], 0, 0, 0);
            acc[1][q] = __builtin_amdgcn_mfma_f32_16x16x32_bf16(ah1, bh, acc[1][q], 0, 0, 0);
            acc[0][q] = __builtin_amdgcn_mfma_f32_16x16x32_bf16(av0, bh, acc[0][q], 0, 0, 0);
            acc[1][q] = __builtin_amdgcn_mfma_f32_16x16x32_bf16(av1, bh, acc[1][q], 0, 0, 0);
            acc[0][q] = __builtin_amdgcn_mfma_f32_16x16x32_bf16(ah0, bl, acc[0][q], 0, 0, 0);
            acc[1][q] = __builtin_amdgcn_mfma_f32_16x16x32_bf16(ah1, bl, acc[1][q], 0, 0, 0);
        }
    }
    gemm_epilogue(acc, lane, wave, rowbase, alv, arv, feat_f16, el, er);
}

// ---------------- MFMA GEMM layer-2 (both paths): A = bf16 hi/lo ----------------
__global__ __launch_bounds__(256) void mfma_gemm_bf(
    const unsigned short* __restrict__ hhi_all, const unsigned short* __restrict__ hlo_all,
    const unsigned short* __restrict__ bphi_all, const unsigned short* __restrict__ bplo_all,
    const float* __restrict__ al_all, const float* __restrict__ ar_all,
    unsigned short* __restrict__ feat_all, float* __restrict__ el_all, float* __restrict__ er_all)
{
    const int p = blockIdx.y;
    const int q4 = p * 2 + 1;
    const unsigned short* hhi = hhi_all + (size_t)p * NND * EMB;
    const unsigned short* hlo = hlo_all + (size_t)p * NND * EMB;
    const unsigned short* bphi = bphi_all + (size_t)q4 * 16384;
    const unsigned short* bplo = bplo_all + (size_t)q4 * 16384;
    const float* alv = al_all + (size_t)q4 * NH * HD;
    const float* arv = ar_all + (size_t)q4 * NH * HD;
    unsigned short* feat_f16 = feat_all + (size_t)p * NND * EMB;
    float* el = el_all + (size_t)p * NND * NH;
    float* er = er_all + (size_t)p * NND * NH;

    const int lane = threadIdx.x & 63;
    const int wave = threadIdx.x >> 6;
    const int rowbase = blockIdx.x * 32;

    f32x4 acc[2][2];
    #pragma unroll
    for (int m = 0; m < 2; ++m)
        #pragma unroll
        for (int q = 0; q < 2; ++q)
            acc[m][q] = (f32x4){0.f, 0.f, 0.f, 0.f};

    const int ar0 = rowbase + (lane & 15);
    const int ar1 = ar0 + 16;
    const int car0 = ar0 < NND ? ar0 : NND - 1;
    const int car1 = ar1 < NND ? ar1 : NND - 1;
    const int kofs = (lane >> 4) * 8;

    #pragma unroll
    for (int kt = 0; kt < 4; ++kt) {
        const int k0 = kt * 32 + kofs;
        short8v ah0 = *reinterpret_cast<const short8v*>(hhi + (size_t)car0 * EMB + k0);
        short8v av0 = *reinterpret_cast<const short8v*>(hlo + (size_t)car0 * EMB + k0);
        short8v ah1 = *reinterpret_cast<const short8v*>(hhi + (size_t)car1 * EMB + k0);
        short8v av1 = *reinterpret_cast<const short8v*>(hlo + (size_t)car1 * EMB + k0);
        #pragma unroll
        for (int q = 0; q < 2; ++q) {
            const int nn = wave * 2 + q;
            const size_t bofs = ((size_t)(nn * 4 + kt) * 64 + lane) * 8;
            short8v bh = *reinterpret_cast<const short8v*>(bphi + bofs);
            short8v bl = *reinterpret_cast<const short8v*>(bplo + bofs);
            acc[0][q] = __builtin_amdgcn_mfma_f32_16x16x32_bf16(ah0, bh, acc[0][q], 0, 0, 0);
            acc[1][q] = __builtin_amdgcn_mfma_f32_16x16x32_bf16(ah1, bh, acc[1][q], 0, 0, 0);
            acc[0][q] = __builtin_amdgcn_mfma_f32_16x16x32_bf16(av0, bh, acc[0][q], 0, 0, 0);
            acc[1][q] = __builtin_amdgcn_mfma_f32_16x16x32_bf16(av1, bh, acc[1][q], 0, 0, 0);
            acc[0][q] = __builtin_amdgcn_mfma_f32_16x16x32_bf16(ah0, bl, acc[0][q], 0, 0, 0);
            acc[1][q] = __builtin_amdgcn_mfma_f32_16x16x32_bf16(ah1, bl, acc[1][q], 0, 0, 0);
        }
    }
    gemm_epilogue(acc, lane, wave, rowbase, alv, arv, feat_f16, el, er);
}

// ---------------- CSR build: both paths (blockIdx.y = path) ----------------
__global__ __launch_bounds__(256) void bucket_count(
    const int* __restrict__ edges, int* __restrict__ bcnt)
{
    const int p = blockIdx.y;
    const int* dst = edges + (size_t)p * 2 * NE + NE;
    __shared__ int hist[NB];
    const int t = threadIdx.x;
    for (int b = t; b < NB; b += 256) hist[b] = 0;
    __syncthreads();
    const int e0 = blockIdx.x * 2048 + t * 8;
    #pragma unroll
    for (int j = 0; j < 8; ++j) {
        int e = e0 + j;
        if (e < NE) atomicAdd(&hist[dst[e] >> 9], 1);
    }
    __syncthreads();
    for (int b = t; b < NB; b += 256)
        if (hist[b]) atomicAdd(&bcnt[p * 128 + b], hist[b]);
}

__global__ __launch_bounds__(128) void scan_bucket(
    const int* __restrict__ bcnt, int* __restrict__ bbase, int* __restrict__ bcur)
{
    const int p = blockIdx.x;
    __shared__ int s[128];
    const int t = threadIdx.x;
    s[t] = (t < NB) ? bcnt[p * 128 + t] : 0;
    __syncthreads();
    for (int off = 1; off < 128; off <<= 1) {
        int v = (t >= off) ? s[t - off] : 0;
        __syncthreads();
        s[t] += v;
        __syncthreads();
    }
    int excl = (t > 0) ? s[t - 1] : 0;
    if (t <= NB) bbase[p * 128 + t] = excl;
    if (t < NB)  bcur[p * 128 + t]  = excl;
}

__global__ __launch_bounds__(256) void bucket_scatter(
    const int* __restrict__ edges, int* __restrict__ bcur, int* __restrict__ ebuf)
{
    const int p = blockIdx.y;
    const int* src = edges + (size_t)p * 2 * NE;
    const int* dst = src + NE;
    int* eb = ebuf + (size_t)p * NE;
    __shared__ int hist[NB];
    __shared__ int base[NB];
    __shared__ int lcur[NB];
    const int t  = threadIdx.x;
    const int e0 = blockIdx.x * 2048 + t * 8;

    for (int b = t; b < NB; b += 256) { hist[b] = 0; lcur[b] = 0; }
    __syncthreads();

    int sj[8], dj[8];
    bool vj[8];
    #pragma unroll
    for (int j = 0; j < 8; ++j) {
        int e = e0 + j;
        vj[j] = (e < NE);
        if (vj[j]) {
            sj[j] = src[e];
            dj[j] = dst[e];
            atomicAdd(&hist[dj[j] >> 9], 1);
        }
    }
    __syncthreads();
    for (int b = t; b < NB; b += 256) {
        int c = hist[b];
        base[b] = c > 0 ? atomicAdd(&bcur[p * 128 + b], c) : 0;
    }
    __syncthreads();
    #pragma unroll
    for (int j = 0; j < 8; ++j) {
        if (vj[j]) {
            int b   = dj[j] >> 9;
            int off = atomicAdd(&lcur[b], 1);
            eb[(size_t)base[b] + off] = (sj[j] << 9) | (dj[j] & 511);
        }
    }
}

__global__ __launch_bounds__(1024) void bucket_fill(
    const int* __restrict__ bbase, const int* __restrict__ ebuf,
    int* __restrict__ rowptr, int* __restrict__ csrsrc)
{
    const int p = blockIdx.y;
    const int* eb = ebuf + (size_t)p * NE;
    int* rp = rowptr + (size_t)p * (NND + 1);
    int* cs = csrsrc + (size_t)p * NE;
    __shared__ int hist[512];
    __shared__ int excl[512];
    const int b    = blockIdx.x;
    const int n0   = b << 9;
    const int t    = threadIdx.x;
    const int base = bbase[p * 128 + b];
    const int cnt  = bbase[p * 128 + b + 1] - base;

    if (t < 512) hist[t] = 0;
    __syncthreads();
    for (int i = t; i < cnt; i += 1024)
        atomicAdd(&hist[eb[base + i] & 511], 1);
    __syncthreads();
    if (t < 512) excl[t] = hist[t];
    __syncthreads();
    for (int off = 1; off < 512; off <<= 1) {
        int v = 0;
        if (t < 512 && t >= off) v = excl[t - off];
        __syncthreads();
        if (t < 512) excl[t] += v;
        __syncthreads();
    }
    if (t < 512) {
        int e = excl[t] - hist[t];
        int n = n0 + t;
        if (n < NND) rp[n] = base + e;
        hist[t] = e;
    }
    if (b == NB - 1 && t == 0) rp[NND] = NE;
    __syncthreads();
    for (int i = t; i < cnt; i += 1024) {
        int ed = eb[base + i];
        int q = atomicAdd(&hist[ed & 511], 1);
        cs[base + q] = ed >> 9;
    }
}

// ---------------- Gather-aggregate (both paths): one wave per destination node ----------------
// Two-phase chunk: phase A = 2 coalesced exps/lane (lane: edge=lane>>3, head=lane&7);
// phase B = 16-deep feat MLP with shfl-broadcast weights. esum via shfl_xor, free.
__global__ __launch_bounds__(256) void gather_agg(
    const int* __restrict__ rowptr_all, const int* __restrict__ csrsrc_all,
    const float* __restrict__ el_all, const float* __restrict__ er_all,
    const unsigned int* __restrict__ feat_all,
    const float* __restrict__ fs,               // layer0 residual
    const unsigned int* __restrict__ hhi_all,   // l0: out; l1: residual
    const unsigned int* __restrict__ hlo_all,
    const float* __restrict__ bias_all,
    float* __restrict__ esum_all,
    float* __restrict__ out_emb,                // layer1 out
    int layer)
{
    const int p    = blockIdx.y;
    const int wid  = (blockIdx.x * blockDim.x + threadIdx.x) >> 6;
    const int lane = threadIdx.x & 63;
    if (wid >= NND) return;
    const int n  = wid;
    const int hB = lane >> 3;   // phase-B head (feat dims)
    const int eA = lane >> 3;   // phase-A edge slot
    const int hA = lane & 7;    // phase-A head

    const int* rowptr = rowptr_all + (size_t)p * (NND + 1);
    const int* csrsrc = csrsrc_all + (size_t)p * NE;
    const float* el   = el_all + (size_t)p * NND * NH;
    const float* er   = er_all + (size_t)p * NND * NH;
    const unsigned int* featu = feat_all + (size_t)p * NND * 64;
    const float* bias = bias_all + (size_t)(p * 2 + layer) * EMB;

    const float ern_a = er[n * NH + hA];
    const int r0 = __builtin_amdgcn_readfirstlane(rowptr[n]);
    const int r1 = __builtin_amdgcn_readfirstlane(rowptr[n + 1]);

    float acc0 = 0.f, acc1 = 0.f, esp = 0.f;

    int i = r0;
    for (; i + 16 <= r1; i += 16) {
        int sj[16];
        #pragma unroll
        for (int j = 0; j < 16; ++j) sj[j] = csrsrc[i + j];          // uniform
        // phase A: 2 exps per lane, coalesced el rows
        float wa = __expf(lrelu(el[sj[eA] * NH + hA] + ern_a));
        float wb = __expf(lrelu(el[sj[eA + 8] * NH + hA] + ern_a));
        esp += wa + wb;
        // phase B: 16 feat gathers in flight
        unsigned int vs[16];
        #pragma unroll
        for (int j = 0; j < 16; ++j) vs[j] = featu[(size_t)sj[j] * 64 + lane];
        #pragma unroll
        for (int j = 0; j < 16; ++j) {
            float wj = __shfl(j < 8 ? wa : wb, ((j & 7) << 3) | hB);
            __half2 v = *reinterpret_cast<__half2*>(&vs[j]);
            acc0 = fmaf(wj, __half2float(__low2half(v)), acc0);
            acc1 = fmaf(wj, __half2float(__high2half(v)), acc1);
        }
    }
    if (i < r1) {
        const int m = r1 - i;                              // 1..15, wave-uniform
        int sj[16];
        #pragma unroll
        for (int j = 0; j < 16; ++j) sj[j] = csrsrc[(i + j < r1) ? i + j : r1 - 1];
        float wa = 0.f, wb = 0.f;
        if (eA < m)     wa = __expf(lrelu(el[sj[eA] * NH + hA] + ern_a));
        if (eA + 8 < m) wb = __expf(lrelu(el[sj[eA + 8] * NH + hA] + ern_a));
        esp += wa + wb;
        #pragma unroll
        for (int j = 0; j < 16; ++j) {
            if (j >= m) break;                             // uniform
            unsigned int vraw = featu[(size_t)sj[j] * 64 + lane];
            float wj = __shfl(j < 8 ? wa : wb, ((j & 7) << 3) | hB);
            __half2 v = *reinterpret_cast<__half2*>(&vraw);
            acc0 = fmaf(wj, __half2float(__low2half(v)), acc0);
            acc1 = fmaf(wj, __half2float(__high2half(v)), acc1);
        }
    }

    // esum: reduce over the 8 lanes sharing hA (stride-8 lanes)
    esp += __shfl_xor(esp, 8);
    esp += __shfl_xor(esp, 16);
    esp += __shfl_xor(esp, 32);
    if (lane < 8) esum_all[((size_t)p * NND + n) * NH + lane] = esp;
    const float es  = __shfl(esp, hB);                     // total for phase-B head
    const float inv = 1.f / fmaxf(es, 1e-9f);

    float h0, h1;
    if (layer == 0) {
        float2 hv = reinterpret_cast<const float2*>(fs + (size_t)p * NND * EMB)[(size_t)n * 64 + lane];
        h0 = hv.x; h1 = hv.y;
    } else {
        unsigned int hiu = hhi_all[((size_t)p * NND + n) * 64 + lane];
        unsigned int lou = hlo_all[((size_t)p * NND + n) * 64 + lane];
        h0 = __uint_as_float(hiu << 16) + __uint_as_float(lou << 16);
        h1 = __uint_as_float(hiu & 0xffff0000u) + __uint_as_float(lou & 0xffff0000u);
    }
    float o0 = elu(fmaf(acc0, inv, h0 + bias[lane * 2]));
    float o1 = elu(fmaf(acc1, inv, h1 + bias[lane * 2 + 1]));

    if (layer == 1) {
        reinterpret_cast<float2*>(out_emb + (size_t)p * NND * EMB)[(size_t)n * 64 + lane] =
            make_float2(o0, o1);
    } else {
        unsigned short hi0 = f2bf(o0), hi1 = f2bf(o1);
        unsigned short lo0 = f2bf(o0 - bf2f(hi0)), lo1 = f2bf(o1 - bf2f(hi1));
        const size_t idx = ((size_t)p * NND + n) * 64 + lane;
        const_cast<unsigned int*>(hhi_all)[idx] = (unsigned int)hi0 | ((unsigned int)hi1 << 16);
        const_cast<unsigned int*>(hlo_all)[idx] = (unsigned int)lo0 | ((unsigned int)lo1 << 16);
    }
}

// ---------------- alpha (both paths): one thread per edge, all 8 heads ----------------
__global__ __launch_bounds__(256) void alpha_write8(
    const int* __restrict__ edges,
    const float* __restrict__ el_all, const float* __restrict__ er_all,
    const float* __restrict__ esum_all, float* __restrict__ out_alpha)
{
    const int p = blockIdx.y;
    int e = blockIdx.x * 256 + threadIdx.x;
    if (e >= NE) return;
    const int* src = edges + (size_t)p * 2 * NE;
    const int* dst = src + NE;
    const float* el   = el_all   + (size_t)p * NND * NH;
    const float* er   = er_all   + (size_t)p * NND * NH;
    const float* esum = esum_all + (size_t)p * NND * NH;
    int s = src[e], d = dst[e];
    const float4* el4 = reinterpret_cast<const float4*>(el + (size_t)s * 8);
    const float4* er4 = reinterpret_cast<const float4*>(er + (size_t)d * 8);
    const float4* es4 = reinterpret_cast<const float4*>(esum + (size_t)d * 8);
    float4 L0 = el4[0], L1 = el4[1];
    float4 R0 = er4[0], R1 = er4[1];
    float4 S0 = es4[0], S1 = es4[1];
    float4 a0, a1;
    a0.x = __fdividef(__expf(lrelu(L0.x + R0.x)), fmaxf(S0.x, 1e-9f));
    a0.y = __fdividef(__expf(lrelu(L0.y + R0.y)), fmaxf(S0.y, 1e-9f));
    a0.z = __fdividef(__expf(lrelu(L0.z + R0.z)), fmaxf(S0.z, 1e-9f));
    a0.w = __fdividef(__expf(lrelu(L0.w + R0.w)), fmaxf(S0.w, 1e-9f));
    a1.x = __fdividef(__expf(lrelu(L1.x + R1.x)), fmaxf(S1.x, 1e-9f));
    a1.y = __fdividef(__expf(lrelu(L1.y + R1.y)), fmaxf(S1.y, 1e-9f));
    a1.z = __fdividef(__expf(lrelu(L1.z + R1.z)), fmaxf(S1.z, 1e-9f));
    a1.w = __fdividef(__expf(lrelu(L1.w + R1.w)), fmaxf(S1.w, 1e-9f));
    float4* o4 = reinterpret_cast<float4*>(out_alpha + ((size_t)p * NE + e) * 8);
    o4[0] = a0;
    o4[1] = a1;
}

extern "C" void kernel_launch(void* const* d_in, const int* in_sizes, int n_in,
                              void* d_out, int out_size, void* d_ws, size_t ws_size,
                              hipStream_t stream) {
    const float* fs   = (const float*)d_in[0];  // [2][N][128]
    const float* W    = (const float*)d_in[1];  // [2][2][128][128]
    const float* al   = (const float*)d_in[2];  // [2][2][8][16]
    const float* ar   = (const float*)d_in[3];  // [2][2][8][16]
    const float* bias = (const float*)d_in[4];  // [2][2][128]
    const int*   edges= (const int*)d_in[5];    // [2][2][E]

    float* out       = (float*)d_out;
    float* out_emb   = out;                              // [2][N][128]
    float* out_alpha = out + (size_t)2 * NND * EMB;      // [2][E][8]

    char* ws = (char*)d_ws;
    auto take = [&](size_t bytes) {
        char* r = ws;
        ws += (bytes + 15) & ~(size_t)15;
        return r;
    };
    unsigned short* feat_f16 = (unsigned short*)take((size_t)2 * NND * EMB * 2);  // [2][N][128] f16
    unsigned short* hhi      = (unsigned short*)take((size_t)2 * NND * EMB * 2);
    unsigned short* hlo      = (unsigned short*)take((size_t)2 * NND * EMB * 2);  // ebuf aliases here
    float*          el       = (float*)take((size_t)2 * NND * NH * 4);
    float*          er       = (float*)take((size_t)2 * NND * NH * 4);
    float*          esum     = (float*)take((size_t)2 * NND * NH * 4);
    int*            rowptr   = (int*)take((size_t)2 * (NND + 1) * 4);
    int*            bcnt     = (int*)take((size_t)2 * 128 * 4);
    int*            bbase    = (int*)take((size_t)2 * 128 * 4);
    int*            bcur     = (int*)take((size_t)2 * 128 * 4);
    int*            csrsrc   = (int*)take((size_t)2 * NE * 4);
    unsigned short* bphi     = (unsigned short*)take((size_t)4 * 16384 * 2);
    unsigned short* bplo     = (unsigned short*)take((size_t)4 * 16384 * 2);

    int*          ebuf  = (int*)hlo;            // dead until gather l0 writes hlo
    unsigned int* featu = (unsigned int*)feat_f16;
    unsigned int* hhi_u = (unsigned int*)hhi;
    unsigned int* hlo_u = (unsigned int*)hlo;

    // --- CSR build, both paths ---
    hipMemsetAsync(bcnt, 0, (size_t)2 * 128 * 4, stream);
    bucket_count<<<dim3((NE + 2047) / 2048, 2), 256, 0, stream>>>(edges, bcnt);
    scan_bucket<<<2, 128, 0, stream>>>(bcnt, bbase, bcur);
    bucket_scatter<<<dim3((NE + 2047) / 2048, 2), 256, 0, stream>>>(edges, bcur, ebuf);
    bucket_fill<<<dim3(NB, 2), 1024, 0, stream>>>(bbase, ebuf, rowptr, csrsrc);

    // --- weights ---
    wpack4<<<32, 256, 0, stream>>>(W, bphi, bplo);

    // --- layer 0 (both paths per launch) ---
    mfma_gemm_f32<<<dim3((NND + 31) / 32, 2), 256, 0, stream>>>(
        fs, bphi, bplo, al, ar, feat_f16, el, er);
    gather_agg<<<dim3((NND + 3) / 4, 2), 256, 0, stream>>>(
        rowptr, csrsrc, el, er, featu, fs, hhi_u, hlo_u, bias, esum, nullptr, 0);

    // --- layer 1 (both paths per launch) ---
    mfma_gemm_bf<<<dim3((NND + 31) / 32, 2), 256, 0, stream>>>(
        hhi, hlo, bphi, bplo, al, ar, feat_f16, el, er);
    gather_agg<<<dim3((NND + 3) / 4, 2), 256, 0, stream>>>(
        rowptr, csrsrc, el, er, featu, fs, hhi_u, hlo_u, bias, esum, out_emb, 1);
    alpha_write8<<<dim3((NE + 255) / 256, 2), 256, 0, stream>>>(
        edges, el, er, esum, out_alpha);
}

// Round 16
// 593.403 us; speedup vs baseline: 1.1181x; 1.0447x over previous
//
#include <hip/hip_runtime.h>
#include <hip/hip_bf16.h>
#include <hip/hip_fp16.h>

#define NND 50000
#define NE  1600000
#define EMB 128
#define NH  8
#define HD  16
#define NB  98            // ceil(50000/512) buckets of 512 dst nodes

typedef __attribute__((ext_vector_type(8))) short short8v;
typedef __attribute__((ext_vector_type(4))) float f32x4;

__device__ __forceinline__ float lrelu(float x) { return x > 0.f ? x : 0.2f * x; }
__device__ __forceinline__ float elu(float x)   { return x > 0.f ? x : expm1f(x); }

__device__ __forceinline__ unsigned short f2bf(float x) {
    __hip_bfloat16 b = __float2bfloat16(x);
    return *reinterpret_cast<unsigned short*>(&b);
}
__device__ __forceinline__ float bf2f(unsigned short u) {
    __hip_bfloat16 b = *reinterpret_cast<__hip_bfloat16*>(&u);
    return __bfloat162float(b);
}

// ---------------- pack all 4 W matrices into per-fragment bf16 hi/lo ----------------
__global__ __launch_bounds__(256) void wpack4(
    const float* __restrict__ W, unsigned short* __restrict__ bphi, unsigned short* __restrict__ bplo)
{
    int s = blockIdx.x * 256 + threadIdx.x;   // grid 32 x 256 = 8192 = 4*2048
    int q    = s >> 11;
    int sidx = s & 2047;
    int n    = sidx >> 8;
    int kt   = (sidx >> 6) & 3;
    int lane = sidx & 63;
    int col  = n * 16 + (lane & 15);
    int krow = kt * 32 + ((lane >> 4) << 3);
    const float* Wm = W + (size_t)q * EMB * EMB;
    #pragma unroll
    for (int j = 0; j < 8; ++j) {
        float x = Wm[(size_t)(krow + j) * EMB + col];
        unsigned short hi = f2bf(x);
        unsigned short lo = f2bf(x - bf2f(hi));
        bphi[(size_t)s * 8 + j] = hi;
        bplo[(size_t)s * 8 + j] = lo;
    }
}

// ---------------- shared GEMM epilogue (feat f16) ----------------
__device__ __forceinline__ void gemm_epilogue(
    f32x4 acc[2][2], int lane, int wave, int rowbase,
    const float* __restrict__ alv, const float* __restrict__ arv,
    unsigned short* __restrict__ feat_f16, float* __restrict__ el, float* __restrict__ er)
{
    const int colr = lane & 15;
    const int rgrp = lane >> 4;
    #pragma unroll
    for (int m = 0; m < 2; ++m) {
        const int row0 = rowbase + m * 16 + rgrp * 4;
        #pragma unroll
        for (int q = 0; q < 2; ++q) {
            const int nn = wave * 2 + q;
            f32x4 a = acc[m][q];
            #pragma unroll
            for (int r = 0; r < 4; ++r) {
                if (row0 + r < NND)
                    feat_f16[(size_t)(row0 + r) * EMB + nn * 16 + colr] =
                        __half_as_ushort(__float2half(a[r]));
            }
            const float alc = alv[nn * 16 + colr];
            const float arc = arv[nn * 16 + colr];
            float pl[4], pr[4];
            #pragma unroll
            for (int r = 0; r < 4; ++r) { pl[r] = a[r] * alc; pr[r] = a[r] * arc; }
            #pragma unroll
            for (int mask = 1; mask < 16; mask <<= 1) {
                #pragma unroll
                for (int r = 0; r < 4; ++r) {
                    pl[r] += __shfl_xor(pl[r], mask);
                    pr[r] += __shfl_xor(pr[r], mask);
                }
            }
            if (colr == 0) {
                #pragma unroll
                for (int r = 0; r < 4; ++r) {
                    int row = row0 + r;
                    if (row < NND) {
                        el[row * NH + nn] = pl[r];
                        er[row * NH + nn] = pr[r];
                    }
                }
            }
        }
    }
}

// ---------------- MFMA GEMM layer-1 (both paths): A = f32 fs, split in-register ----------------
__global__ __launch_bounds__(256) void mfma_gemm_f32(
    const float* __restrict__ fs,
    const unsigned short* __restrict__ bphi_all, const unsigned short* __restrict__ bplo_all,
    const float* __restrict__ al_all, const float* __restrict__ ar_all,
    unsigned short* __restrict__ feat_all, float* __restrict__ el_all, float* __restrict__ er_all)
{
    const int p = blockIdx.y;
    const int q4 = p * 2;
    const float* hin = fs + (size_t)p * NND * EMB;
    const unsigned short* bphi = bphi_all + (size_t)q4 * 16384;
    const unsigned short* bplo = bplo_all + (size_t)q4 * 16384;
    const float* alv = al_all + (size_t)q4 * NH * HD;
    const float* arv = ar_all + (size_t)q4 * NH * HD;
    unsigned short* feat_f16 = feat_all + (size_t)p * NND * EMB;
    float* el = el_all + (size_t)p * NND * NH;
    float* er = er_all + (size_t)p * NND * NH;

    const int lane = threadIdx.x & 63;
    const int wave = threadIdx.x >> 6;
    const int rowbase = blockIdx.x * 32;

    f32x4 acc[2][2];
    #pragma unroll
    for (int m = 0; m < 2; ++m)
        #pragma unroll
        for (int q = 0; q < 2; ++q)
            acc[m][q] = (f32x4){0.f, 0.f, 0.f, 0.f};

    const int ar0 = rowbase + (lane & 15);
    const int ar1 = ar0 + 16;
    const int car0 = ar0 < NND ? ar0 : NND - 1;
    const int car1 = ar1 < NND ? ar1 : NND - 1;
    const int kofs = (lane >> 4) * 8;

    #pragma unroll
    for (int kt = 0; kt < 4; ++kt) {
        const int k0 = kt * 32 + kofs;
        short8v ah0, av0, ah1, av1;
        {
            const float4* fr = reinterpret_cast<const float4*>(hin + (size_t)car0 * EMB + k0);
            float4 x0 = fr[0], x1 = fr[1];
            float xs[8] = { x0.x, x0.y, x0.z, x0.w, x1.x, x1.y, x1.z, x1.w };
            #pragma unroll
            for (int j = 0; j < 8; ++j) {
                unsigned short hi = f2bf(xs[j]);
                ah0[j] = (short)hi;
                av0[j] = (short)f2bf(xs[j] - bf2f(hi));
            }
        }
        {
            const float4* fr = reinterpret_cast<const float4*>(hin + (size_t)car1 * EMB + k0);
            float4 x0 = fr[0], x1 = fr[1];
            float xs[8] = { x0.x, x0.y, x0.z, x0.w, x1.x, x1.y, x1.z, x1.w };
            #pragma unroll
            for (int j = 0; j < 8; ++j) {
                unsigned short hi = f2bf(xs[j]);
                ah1[j] = (short)hi;
                av1[j] = (short)f2bf(xs[j] - bf2f(hi));
            }
        }
        #pragma unroll
        for (int q = 0; q < 2; ++q) {
            const int nn = wave * 2 + q;
            const size_t bofs = ((size_t)(nn * 4 + kt) * 64 + lane) * 8;
            short8v bh = *reinterpret_cast<const short8v*>(bphi + bofs);
            short8v bl = *reinterpret_cast<const short8v*>(bplo + bofs);
            acc[0][q] = __builtin_amdgcn_mfma_f32_16x16x32_bf16(ah0, bh, acc[0][q], 0, 0, 0);
            acc[1][q] = __builtin_amdgcn_mfma_f32_16x16x32_bf16(ah1, bh, acc[1][q], 0, 0, 0);
            acc[0][q] = __builtin_amdgcn_mfma_f32_16x16x32_bf16(av0, bh, acc[0][q], 0, 0, 0);
            acc[1][q] = __builtin_amdgcn_mfma_f32_16x16x32_bf16(av1, bh, acc[1][q], 0, 0, 0);
            acc[0][q] = __builtin_amdgcn_mfma_f32_16x16x32_bf16(ah0, bl, acc[0][q], 0, 0, 0);
            acc[1][q] = __builtin_amdgcn_mfma_f32_16x16x32_bf16(ah1, bl, acc[1][q], 0, 0, 0);
        }
    }
    gemm_epilogue(acc, lane, wave, rowbase, alv, arv, feat_f16, el, er);
}

// ---------------- MFMA GEMM layer-2 (both paths): A = bf16 hi/lo ----------------
__global__ __launch_bounds__(256) void mfma_gemm_bf(
    const unsigned short* __restrict__ hhi_all, const unsigned short* __restrict__ hlo_all,
    const unsigned short* __restrict__ bphi_all, const unsigned short* __restrict__ bplo_all,
    const float* __restrict__ al_all, const float* __restrict__ ar_all,
    unsigned short* __restrict__ feat_all, float* __restrict__ el_all, float* __restrict__ er_all)
{
    const int p = blockIdx.y;
    const int q4 = p * 2 + 1;
    const unsigned short* hhi = hhi_all + (size_t)p * NND * EMB;
    const unsigned short* hlo = hlo_all + (size_t)p * NND * EMB;
    const unsigned short* bphi = bphi_all + (size_t)q4 * 16384;
    const unsigned short* bplo = bplo_all + (size_t)q4 * 16384;
    const float* alv = al_all + (size_t)q4 * NH * HD;
    const float* arv = ar_all + (size_t)q4 * NH * HD;
    unsigned short* feat_f16 = feat_all + (size_t)p * NND * EMB;
    float* el = el_all + (size_t)p * NND * NH;
    float* er = er_all + (size_t)p * NND * NH;

    const int lane = threadIdx.x & 63;
    const int wave = threadIdx.x >> 6;
    const int rowbase = blockIdx.x * 32;

    f32x4 acc[2][2];
    #pragma unroll
    for (int m = 0; m < 2; ++m)
        #pragma unroll
        for (int q = 0; q < 2; ++q)
            acc[m][q] = (f32x4){0.f, 0.f, 0.f, 0.f};

    const int ar0 = rowbase + (lane & 15);
    const int ar1 = ar0 + 16;
    const int car0 = ar0 < NND ? ar0 : NND - 1;
    const int car1 = ar1 < NND ? ar1 : NND - 1;
    const int kofs = (lane >> 4) * 8;

    #pragma unroll
    for (int kt = 0; kt < 4; ++kt) {
        const int k0 = kt * 32 + kofs;
        short8v ah0 = *reinterpret_cast<const short8v*>(hhi + (size_t)car0 * EMB + k0);
        short8v av0 = *reinterpret_cast<const short8v*>(hlo + (size_t)car0 * EMB + k0);
        short8v ah1 = *reinterpret_cast<const short8v*>(hhi + (size_t)car1 * EMB + k0);
        short8v av1 = *reinterpret_cast<const short8v*>(hlo + (size_t)car1 * EMB + k0);
        #pragma unroll
        for (int q = 0; q < 2; ++q) {
            const int nn = wave * 2 + q;
            const size_t bofs = ((size_t)(nn * 4 + kt) * 64 + lane) * 8;
            short8v bh = *reinterpret_cast<const short8v*>(bphi + bofs);
            short8v bl = *reinterpret_cast<const short8v*>(bplo + bofs);
            acc[0][q] = __builtin_amdgcn_mfma_f32_16x16x32_bf16(ah0, bh, acc[0][q], 0, 0, 0);
            acc[1][q] = __builtin_amdgcn_mfma_f32_16x16x32_bf16(ah1, bh, acc[1][q], 0, 0, 0);
            acc[0][q] = __builtin_amdgcn_mfma_f32_16x16x32_bf16(av0, bh, acc[0][q], 0, 0, 0);
            acc[1][q] = __builtin_amdgcn_mfma_f32_16x16x32_bf16(av1, bh, acc[1][q], 0, 0, 0);
            acc[0][q] = __builtin_amdgcn_mfma_f32_16x16x32_bf16(ah0, bl, acc[0][q], 0, 0, 0);
            acc[1][q] = __builtin_amdgcn_mfma_f32_16x16x32_bf16(ah1, bl, acc[1][q], 0, 0, 0);
        }
    }
    gemm_epilogue(acc, lane, wave, rowbase, alv, arv, feat_f16, el, er);
}

// ---------------- CSR build: both paths (blockIdx.y = path) ----------------
__global__ __launch_bounds__(256) void bucket_count(
    const int* __restrict__ edges, int* __restrict__ bcnt)
{
    const int p = blockIdx.y;
    const int* dst = edges + (size_t)p * 2 * NE + NE;
    __shared__ int hist[NB];
    const int t = threadIdx.x;
    for (int b = t; b < NB; b += 256) hist[b] = 0;
    __syncthreads();
    const int e0 = blockIdx.x * 2048 + t * 8;
    #pragma unroll
    for (int j = 0; j < 8; ++j) {
        int e = e0 + j;
        if (e < NE) atomicAdd(&hist[dst[e] >> 9], 1);
    }
    __syncthreads();
    for (int b = t; b < NB; b += 256)
        if (hist[b]) atomicAdd(&bcnt[p * 128 + b], hist[b]);
}

__global__ __launch_bounds__(128) void scan_bucket(
    const int* __restrict__ bcnt, int* __restrict__ bbase, int* __restrict__ bcur)
{
    const int p = blockIdx.x;
    __shared__ int s[128];
    const int t = threadIdx.x;
    s[t] = (t < NB) ? bcnt[p * 128 + t] : 0;
    __syncthreads();
    for (int off = 1; off < 128; off <<= 1) {
        int v = (t >= off) ? s[t - off] : 0;
        __syncthreads();
        s[t] += v;
        __syncthreads();
    }
    int excl = (t > 0) ? s[t - 1] : 0;
    if (t <= NB) bbase[p * 128 + t] = excl;
    if (t < NB)  bcur[p * 128 + t]  = excl;
}

__global__ __launch_bounds__(256) void bucket_scatter(
    const int* __restrict__ edges, int* __restrict__ bcur, int* __restrict__ ebuf)
{
    const int p = blockIdx.y;
    const int* src = edges + (size_t)p * 2 * NE;
    const int* dst = src + NE;
    int* eb = ebuf + (size_t)p * NE;
    __shared__ int hist[NB];
    __shared__ int base[NB];
    __shared__ int lcur[NB];
    const int t  = threadIdx.x;
    const int e0 = blockIdx.x * 2048 + t * 8;

    for (int b = t; b < NB; b += 256) { hist[b] = 0; lcur[b] = 0; }
    __syncthreads();

    int sj[8], dj[8];
    bool vj[8];
    #pragma unroll
    for (int j = 0; j < 8; ++j) {
        int e = e0 + j;
        vj[j] = (e < NE);
        if (vj[j]) {
            sj[j] = src[e];
            dj[j] = dst[e];
            atomicAdd(&hist[dj[j] >> 9], 1);
        }
    }
    __syncthreads();
    for (int b = t; b < NB; b += 256) {
        int c = hist[b];
        base[b] = c > 0 ? atomicAdd(&bcur[p * 128 + b], c) : 0;
    }
    __syncthreads();
    #pragma unroll
    for (int j = 0; j < 8; ++j) {
        if (vj[j]) {
            int b   = dj[j] >> 9;
            int off = atomicAdd(&lcur[b], 1);
            eb[(size_t)base[b] + off] = (sj[j] << 9) | (dj[j] & 511);
        }
    }
}

__global__ __launch_bounds__(1024) void bucket_fill(
    const int* __restrict__ bbase, const int* __restrict__ ebuf,
    int* __restrict__ rowptr, int* __restrict__ csrsrc)
{
    const int p = blockIdx.y;
    const int* eb = ebuf + (size_t)p * NE;
    int* rp = rowptr + (size_t)p * (NND + 1);
    int* cs = csrsrc + (size_t)p * NE;
    __shared__ int hist[512];
    __shared__ int excl[512];
    const int b    = blockIdx.x;
    const int n0   = b << 9;
    const int t    = threadIdx.x;
    const int base = bbase[p * 128 + b];
    const int cnt  = bbase[p * 128 + b + 1] - base;

    if (t < 512) hist[t] = 0;
    __syncthreads();
    for (int i = t; i < cnt; i += 1024)
        atomicAdd(&hist[eb[base + i] & 511], 1);
    __syncthreads();
    if (t < 512) excl[t] = hist[t];
    __syncthreads();
    for (int off = 1; off < 512; off <<= 1) {
        int v = 0;
        if (t < 512 && t >= off) v = excl[t - off];
        __syncthreads();
        if (t < 512) excl[t] += v;
        __syncthreads();
    }
    if (t < 512) {
        int e = excl[t] - hist[t];
        int n = n0 + t;
        if (n < NND) rp[n] = base + e;
        hist[t] = e;
    }
    if (b == NB - 1 && t == 0) rp[NND] = NE;
    __syncthreads();
    for (int i = t; i < cnt; i += 1024) {
        int ed = eb[base + i];
        int q = atomicAdd(&hist[ed & 511], 1);
        cs[base + q] = ed >> 9;
    }
}

// ---------------- Gather-aggregate (both paths): one wave per destination node ----------------
// Two-phase chunk with LDS-transposed weights:
//   phase A (lane: edge=lane>>3, head=lane&7): 2 coalesced exps -> wT[wave][head][slot]
//   phase B (lane: dims, head=lane>>3): 4x ds_read_b128 of wT row, 16-deep feat MLP.
__global__ __launch_bounds__(256) void gather_agg(
    const int* __restrict__ rowptr_all, const int* __restrict__ csrsrc_all,
    const float* __restrict__ el_all, const float* __restrict__ er_all,
    const unsigned int* __restrict__ feat_all,
    const float* __restrict__ fs,               // layer0 residual
    const unsigned int* __restrict__ hhi_all,   // l0: out; l1: residual
    const unsigned int* __restrict__ hlo_all,
    const float* __restrict__ bias_all,
    float* __restrict__ esum_all,
    float* __restrict__ out_emb,                // layer1 out
    int layer)
{
    __shared__ float wT[4][NH][16];             // [wave][head][slot]
    const int p    = blockIdx.y;
    const int wid  = (blockIdx.x * blockDim.x + threadIdx.x) >> 6;
    const int lane = threadIdx.x & 63;
    const int wave = threadIdx.x >> 6;
    if (wid >= NND) return;
    const int n  = wid;
    const int hB = lane >> 3;   // phase-B head (feat dims)
    const int eA = lane >> 3;   // phase-A edge slot
    const int hA = lane & 7;    // phase-A head

    const int* rowptr = rowptr_all + (size_t)p * (NND + 1);
    const int* csrsrc = csrsrc_all + (size_t)p * NE;
    const float* el   = el_all + (size_t)p * NND * NH;
    const float* er   = er_all + (size_t)p * NND * NH;
    const unsigned int* featu = feat_all + (size_t)p * NND * 64;
    const float* bias = bias_all + (size_t)(p * 2 + layer) * EMB;

    const float ern_a = er[n * NH + hA];
    const int r0 = __builtin_amdgcn_readfirstlane(rowptr[n]);
    const int r1 = __builtin_amdgcn_readfirstlane(rowptr[n + 1]);

    float acc0 = 0.f, acc1 = 0.f, esp = 0.f;
    float4* wrow = reinterpret_cast<float4*>(&wT[wave][0][0]) + hB * 4;

    int i = r0;
    for (; i + 16 <= r1; i += 16) {
        int sj[16];
        #pragma unroll
        for (int j = 0; j < 16; ++j) sj[j] = csrsrc[i + j];          // uniform
        // phase A: 2 exps per lane, coalesced el rows; transpose via LDS
        float wa = __expf(lrelu(el[sj[eA] * NH + hA] + ern_a));
        float wb = __expf(lrelu(el[sj[eA + 8] * NH + hA] + ern_a));
        esp += wa + wb;
        wT[wave][hA][eA]     = wa;
        wT[wave][hA][eA + 8] = wb;
        // phase B: 16 feat gathers in flight
        unsigned int vs[16];
        #pragma unroll
        for (int j = 0; j < 16; ++j) vs[j] = featu[(size_t)sj[j] * 64 + lane];
        float4 w4[4];
        #pragma unroll
        for (int j = 0; j < 4; ++j) w4[j] = wrow[j];
        const float* wv = reinterpret_cast<const float*>(w4);
        #pragma unroll
        for (int j = 0; j < 16; ++j) {
            __half2 v = *reinterpret_cast<__half2*>(&vs[j]);
            acc0 = fmaf(wv[j], __half2float(__low2half(v)), acc0);
            acc1 = fmaf(wv[j], __half2float(__high2half(v)), acc1);
        }
    }
    if (i < r1) {
        const int m = r1 - i;                              // 1..15, wave-uniform
        int sj[16];
        #pragma unroll
        for (int j = 0; j < 16; ++j) sj[j] = csrsrc[(i + j < r1) ? i + j : r1 - 1];
        float wa = 0.f, wb = 0.f;
        if (eA < m)     wa = __expf(lrelu(el[sj[eA] * NH + hA] + ern_a));
        if (eA + 8 < m) wb = __expf(lrelu(el[sj[eA + 8] * NH + hA] + ern_a));
        esp += wa + wb;
        wT[wave][hA][eA]     = wa;
        wT[wave][hA][eA + 8] = wb;
        float4 w4[4];
        #pragma unroll
        for (int j = 0; j < 4; ++j) w4[j] = wrow[j];
        const float* wv = reinterpret_cast<const float*>(w4);
        #pragma unroll
        for (int j = 0; j < 16; ++j) {
            if (j >= m) break;                             // uniform
            unsigned int vraw = featu[(size_t)sj[j] * 64 + lane];
            __half2 v = *reinterpret_cast<__half2*>(&vraw);
            acc0 = fmaf(wv[j], __half2float(__low2half(v)), acc0);
            acc1 = fmaf(wv[j], __half2float(__high2half(v)), acc1);
        }
    }

    // esum: reduce over the 8 lanes sharing hA (stride-8 lanes)
    esp += __shfl_xor(esp, 8);
    esp += __shfl_xor(esp, 16);
    esp += __shfl_xor(esp, 32);
    if (lane < 8) esum_all[((size_t)p * NND + n) * NH + lane] = esp;
    const float es  = __shfl(esp, hB);                     // total for phase-B head
    const float inv = 1.f / fmaxf(es, 1e-9f);

    float h0, h1;
    if (layer == 0) {
        float2 hv = reinterpret_cast<const float2*>(fs + (size_t)p * NND * EMB)[(size_t)n * 64 + lane];
        h0 = hv.x; h1 = hv.y;
    } else {
        unsigned int hiu = hhi_all[((size_t)p * NND + n) * 64 + lane];
        unsigned int lou = hlo_all[((size_t)p * NND + n) * 64 + lane];
        h0 = __uint_as_float(hiu << 16) + __uint_as_float(lou << 16);
        h1 = __uint_as_float(hiu & 0xffff0000u) + __uint_as_float(lou & 0xffff0000u);
    }
    float o0 = elu(fmaf(acc0, inv, h0 + bias[lane * 2]));
    float o1 = elu(fmaf(acc1, inv, h1 + bias[lane * 2 + 1]));

    if (layer == 1) {
        reinterpret_cast<float2*>(out_emb + (size_t)p * NND * EMB)[(size_t)n * 64 + lane] =
            make_float2(o0, o1);
    } else {
        unsigned short hi0 = f2bf(o0), hi1 = f2bf(o1);
        unsigned short lo0 = f2bf(o0 - bf2f(hi0)), lo1 = f2bf(o1 - bf2f(hi1));
        const size_t idx = ((size_t)p * NND + n) * 64 + lane;
        const_cast<unsigned int*>(hhi_all)[idx] = (unsigned int)hi0 | ((unsigned int)hi1 << 16);
        const_cast<unsigned int*>(hlo_all)[idx] = (unsigned int)lo0 | ((unsigned int)lo1 << 16);
    }
}

// ---------------- alpha (both paths): one thread per edge, all 8 heads ----------------
__global__ __launch_bounds__(256) void alpha_write8(
    const int* __restrict__ edges,
    const float* __restrict__ el_all, const float* __restrict__ er_all,
    const float* __restrict__ esum_all, float* __restrict__ out_alpha)
{
    const int p = blockIdx.y;
    int e = blockIdx.x * 256 + threadIdx.x;
    if (e >= NE) return;
    const int* src = edges + (size_t)p * 2 * NE;
    const int* dst = src + NE;
    const float* el   = el_all   + (size_t)p * NND * NH;
    const float* er   = er_all   + (size_t)p * NND * NH;
    const float* esum = esum_all + (size_t)p * NND * NH;
    int s = src[e], d = dst[e];
    const float4* el4 = reinterpret_cast<const float4*>(el + (size_t)s * 8);
    const float4* er4 = reinterpret_cast<const float4*>(er + (size_t)d * 8);
    const float4* es4 = reinterpret_cast<const float4*>(esum + (size_t)d * 8);
    float4 L0 = el4[0], L1 = el4[1];
    float4 R0 = er4[0], R1 = er4[1];
    float4 S0 = es4[0], S1 = es4[1];
    float4 a0, a1;
    a0.x = __fdividef(__expf(lrelu(L0.x + R0.x)), fmaxf(S0.x, 1e-9f));
    a0.y = __fdividef(__expf(lrelu(L0.y + R0.y)), fmaxf(S0.y, 1e-9f));
    a0.z = __fdividef(__expf(lrelu(L0.z + R0.z)), fmaxf(S0.z, 1e-9f));
    a0.w = __fdividef(__expf(lrelu(L0.w + R0.w)), fmaxf(S0.w, 1e-9f));
    a1.x = __fdividef(__expf(lrelu(L1.x + R1.x)), fmaxf(S1.x, 1e-9f));
    a1.y = __fdividef(__expf(lrelu(L1.y + R1.y)), fmaxf(S1.y, 1e-9f));
    a1.z = __fdividef(__expf(lrelu(L1.z + R1.z)), fmaxf(S1.z, 1e-9f));
    a1.w = __fdividef(__expf(lrelu(L1.w + R1.w)), fmaxf(S1.w, 1e-9f));
    float4* o4 = reinterpret_cast<float4*>(out_alpha + ((size_t)p * NE + e) * 8);
    o4[0] = a0;
    o4[1] = a1;
}

extern "C" void kernel_launch(void* const* d_in, const int* in_sizes, int n_in,
                              void* d_out, int out_size, void* d_ws, size_t ws_size,
                              hipStream_t stream) {
    const float* fs   = (const float*)d_in[0];  // [2][N][128]
    const float* W    = (const float*)d_in[1];  // [2][2][128][128]
    const float* al   = (const float*)d_in[2];  // [2][2][8][16]
    const float* ar   = (const float*)d_in[3];  // [2][2][8][16]
    const float* bias = (const float*)d_in[4];  // [2][2][128]
    const int*   edges= (const int*)d_in[5];    // [2][2][E]

    float* out       = (float*)d_out;
    float* out_emb   = out;                              // [2][N][128]
    float* out_alpha = out + (size_t)2 * NND * EMB;      // [2][E][8]

    char* ws = (char*)d_ws;
    auto take = [&](size_t bytes) {
        char* r = ws;
        ws += (bytes + 15) & ~(size_t)15;
        return r;
    };
    unsigned short* feat_f16 = (unsigned short*)take((size_t)2 * NND * EMB * 2);  // [2][N][128] f16
    unsigned short* hhi      = (unsigned short*)take((size_t)2 * NND * EMB * 2);
    unsigned short* hlo      = (unsigned short*)take((size_t)2 * NND * EMB * 2);  // ebuf aliases here
    float*          el       = (float*)take((size_t)2 * NND * NH * 4);
    float*          er       = (float*)take((size_t)2 * NND * NH * 4);
    float*          esum     = (float*)take((size_t)2 * NND * NH * 4);
    int*            rowptr   = (int*)take((size_t)2 * (NND + 1) * 4);
    int*            bcnt     = (int*)take((size_t)2 * 128 * 4);
    int*            bbase    = (int*)take((size_t)2 * 128 * 4);
    int*            bcur     = (int*)take((size_t)2 * 128 * 4);
    int*            csrsrc   = (int*)take((size_t)2 * NE * 4);
    unsigned short* bphi     = (unsigned short*)take((size_t)4 * 16384 * 2);
    unsigned short* bplo     = (unsigned short*)take((size_t)4 * 16384 * 2);

    int*          ebuf  = (int*)hlo;            // dead until gather l0 writes hlo
    unsigned int* featu = (unsigned int*)feat_f16;
    unsigned int* hhi_u = (unsigned int*)hhi;
    unsigned int* hlo_u = (unsigned int*)hlo;

    // --- CSR build, both paths ---
    hipMemsetAsync(bcnt, 0, (size_t)2 * 128 * 4, stream);
    bucket_count<<<dim3((NE + 2047) / 2048, 2), 256, 0, stream>>>(edges, bcnt);
    scan_bucket<<<2, 128, 0, stream>>>(bcnt, bbase, bcur);
    bucket_scatter<<<dim3((NE + 2047) / 2048, 2), 256, 0, stream>>>(edges, bcur, ebuf);
    bucket_fill<<<dim3(NB, 2), 1024, 0, stream>>>(bbase, ebuf, rowptr, csrsrc);

    // --- weights ---
    wpack4<<<32, 256, 0, stream>>>(W, bphi, bplo);

    // --- layer 0 (both paths per launch) ---
    mfma_gemm_f32<<<dim3((NND + 31) / 32, 2), 256, 0, stream>>>(
        fs, bphi, bplo, al, ar, feat_f16, el, er);
    gather_agg<<<dim3((NND + 3) / 4, 2), 256, 0, stream>>>(
        rowptr, csrsrc, el, er, featu, fs, hhi_u, hlo_u, bias, esum, nullptr, 0);

    // --- layer 1 (both paths per launch) ---
    mfma_gemm_bf<<<dim3((NND + 31) / 32, 2), 256, 0, stream>>>(
        hhi, hlo, bphi, bplo, al, ar, feat_f16, el, er);
    gather_agg<<<dim3((NND + 3) / 4, 2), 256, 0, stream>>>(
        rowptr, csrsrc, el, er, featu, fs, hhi_u, hlo_u, bias, esum, out_emb, 1);
    alpha_write8<<<dim3((NE + 255) / 256, 2), 256, 0, stream>>>(
        edges, el, er, esum, out_alpha);
}

// Round 17
// 591.509 us; speedup vs baseline: 1.1217x; 1.0032x over previous
//
#include <hip/hip_runtime.h>
#include <hip/hip_bf16.h>
#include <hip/hip_fp16.h>

#define NND 50000
#define NE  1600000
#define EMB 128
#define NH  8
#define HD  16
#define NB  98            // ceil(50000/512) buckets of 512 dst nodes
#define WSL 20            // padded slot dim: banks (h*20+j*4)%32 cover all 32, conflict-free

typedef __attribute__((ext_vector_type(8))) short short8v;
typedef __attribute__((ext_vector_type(4))) float f32x4;

__device__ __forceinline__ float lrelu(float x) { return x > 0.f ? x : 0.2f * x; }
__device__ __forceinline__ float elu(float x)   { return x > 0.f ? x : expm1f(x); }

__device__ __forceinline__ unsigned short f2bf(float x) {
    __hip_bfloat16 b = __float2bfloat16(x);
    return *reinterpret_cast<unsigned short*>(&b);
}
__device__ __forceinline__ float bf2f(unsigned short u) {
    __hip_bfloat16 b = *reinterpret_cast<__hip_bfloat16*>(&u);
    return __bfloat162float(b);
}

// ---------------- pack all 4 W matrices into per-fragment bf16 hi/lo ----------------
__global__ __launch_bounds__(256) void wpack4(
    const float* __restrict__ W, unsigned short* __restrict__ bphi, unsigned short* __restrict__ bplo)
{
    int s = blockIdx.x * 256 + threadIdx.x;   // grid 32 x 256 = 8192 = 4*2048
    int q    = s >> 11;
    int sidx = s & 2047;
    int n    = sidx >> 8;
    int kt   = (sidx >> 6) & 3;
    int lane = sidx & 63;
    int col  = n * 16 + (lane & 15);
    int krow = kt * 32 + ((lane >> 4) << 3);
    const float* Wm = W + (size_t)q * EMB * EMB;
    #pragma unroll
    for (int j = 0; j < 8; ++j) {
        float x = Wm[(size_t)(krow + j) * EMB + col];
        unsigned short hi = f2bf(x);
        unsigned short lo = f2bf(x - bf2f(hi));
        bphi[(size_t)s * 8 + j] = hi;
        bplo[(size_t)s * 8 + j] = lo;
    }
}

// ---------------- shared GEMM epilogue (feat f16) ----------------
__device__ __forceinline__ void gemm_epilogue(
    f32x4 acc[2][2], int lane, int wave, int rowbase,
    const float* __restrict__ alv, const float* __restrict__ arv,
    unsigned short* __restrict__ feat_f16, float* __restrict__ el, float* __restrict__ er)
{
    const int colr = lane & 15;
    const int rgrp = lane >> 4;
    #pragma unroll
    for (int m = 0; m < 2; ++m) {
        const int row0 = rowbase + m * 16 + rgrp * 4;
        #pragma unroll
        for (int q = 0; q < 2; ++q) {
            const int nn = wave * 2 + q;
            f32x4 a = acc[m][q];
            #pragma unroll
            for (int r = 0; r < 4; ++r) {
                if (row0 + r < NND)
                    feat_f16[(size_t)(row0 + r) * EMB + nn * 16 + colr] =
                        __half_as_ushort(__float2half(a[r]));
            }
            const float alc = alv[nn * 16 + colr];
            const float arc = arv[nn * 16 + colr];
            float pl[4], pr[4];
            #pragma unroll
            for (int r = 0; r < 4; ++r) { pl[r] = a[r] * alc; pr[r] = a[r] * arc; }
            #pragma unroll
            for (int mask = 1; mask < 16; mask <<= 1) {
                #pragma unroll
                for (int r = 0; r < 4; ++r) {
                    pl[r] += __shfl_xor(pl[r], mask);
                    pr[r] += __shfl_xor(pr[r], mask);
                }
            }
            if (colr == 0) {
                #pragma unroll
                for (int r = 0; r < 4; ++r) {
                    int row = row0 + r;
                    if (row < NND) {
                        el[row * NH + nn] = pl[r];
                        er[row * NH + nn] = pr[r];
                    }
                }
            }
        }
    }
}

// ---------------- MFMA GEMM layer-1 (both paths): A = f32 fs, split in-register ----------------
__global__ __launch_bounds__(256) void mfma_gemm_f32(
    const float* __restrict__ fs,
    const unsigned short* __restrict__ bphi_all, const unsigned short* __restrict__ bplo_all,
    const float* __restrict__ al_all, const float* __restrict__ ar_all,
    unsigned short* __restrict__ feat_all, float* __restrict__ el_all, float* __restrict__ er_all)
{
    const int p = blockIdx.y;
    const int q4 = p * 2;
    const float* hin = fs + (size_t)p * NND * EMB;
    const unsigned short* bphi = bphi_all + (size_t)q4 * 16384;
    const unsigned short* bplo = bplo_all + (size_t)q4 * 16384;
    const float* alv = al_all + (size_t)q4 * NH * HD;
    const float* arv = ar_all + (size_t)q4 * NH * HD;
    unsigned short* feat_f16 = feat_all + (size_t)p * NND * EMB;
    float* el = el_all + (size_t)p * NND * NH;
    float* er = er_all + (size_t)p * NND * NH;

    const int lane = threadIdx.x & 63;
    const int wave = threadIdx.x >> 6;
    const int rowbase = blockIdx.x * 32;

    f32x4 acc[2][2];
    #pragma unroll
    for (int m = 0; m < 2; ++m)
        #pragma unroll
        for (int q = 0; q < 2; ++q)
            acc[m][q] = (f32x4){0.f, 0.f, 0.f, 0.f};

    const int ar0 = rowbase + (lane & 15);
    const int ar1 = ar0 + 16;
    const int car0 = ar0 < NND ? ar0 : NND - 1;
    const int car1 = ar1 < NND ? ar1 : NND - 1;
    const int kofs = (lane >> 4) * 8;

    #pragma unroll
    for (int kt = 0; kt < 4; ++kt) {
        const int k0 = kt * 32 + kofs;
        short8v ah0, av0, ah1, av1;
        {
            const float4* fr = reinterpret_cast<const float4*>(hin + (size_t)car0 * EMB + k0);
            float4 x0 = fr[0], x1 = fr[1];
            float xs[8] = { x0.x, x0.y, x0.z, x0.w, x1.x, x1.y, x1.z, x1.w };
            #pragma unroll
            for (int j = 0; j < 8; ++j) {
                unsigned short hi = f2bf(xs[j]);
                ah0[j] = (short)hi;
                av0[j] = (short)f2bf(xs[j] - bf2f(hi));
            }
        }
        {
            const float4* fr = reinterpret_cast<const float4*>(hin + (size_t)car1 * EMB + k0);
            float4 x0 = fr[0], x1 = fr[1];
            float xs[8] = { x0.x, x0.y, x0.z, x0.w, x1.x, x1.y, x1.z, x1.w };
            #pragma unroll
            for (int j = 0; j < 8; ++j) {
                unsigned short hi = f2bf(xs[j]);
                ah1[j] = (short)hi;
                av1[j] = (short)f2bf(xs[j] - bf2f(hi));
            }
        }
        #pragma unroll
        for (int q = 0; q < 2; ++q) {
            const int nn = wave * 2 + q;
            const size_t bofs = ((size_t)(nn * 4 + kt) * 64 + lane) * 8;
            short8v bh = *reinterpret_cast<const short8v*>(bphi + bofs);
            short8v bl = *reinterpret_cast<const short8v*>(bplo + bofs);
            acc[0][q] = __builtin_amdgcn_mfma_f32_16x16x32_bf16(ah0, bh, acc[0][q], 0, 0, 0);
            acc[1][q] = __builtin_amdgcn_mfma_f32_16x16x32_bf16(ah1, bh, acc[1][q], 0, 0, 0);
            acc[0][q] = __builtin_amdgcn_mfma_f32_16x16x32_bf16(av0, bh, acc[0][q], 0, 0, 0);
            acc[1][q] = __builtin_amdgcn_mfma_f32_16x16x32_bf16(av1, bh, acc[1][q], 0, 0, 0);
            acc[0][q] = __builtin_amdgcn_mfma_f32_16x16x32_bf16(ah0, bl, acc[0][q], 0, 0, 0);
            acc[1][q] = __builtin_amdgcn_mfma_f32_16x16x32_bf16(ah1, bl, acc[1][q], 0, 0, 0);
        }
    }
    gemm_epilogue(acc, lane, wave, rowbase, alv, arv, feat_f16, el, er);
}

// ---------------- MFMA GEMM layer-2 (both paths): A = bf16 hi/lo ----------------
__global__ __launch_bounds__(256) void mfma_gemm_bf(
    const unsigned short* __restrict__ hhi_all, const unsigned short* __restrict__ hlo_all,
    const unsigned short* __restrict__ bphi_all, const unsigned short* __restrict__ bplo_all,
    const float* __restrict__ al_all, const float* __restrict__ ar_all,
    unsigned short* __restrict__ feat_all, float* __restrict__ el_all, float* __restrict__ er_all)
{
    const int p = blockIdx.y;
    const int q4 = p * 2 + 1;
    const unsigned short* hhi = hhi_all + (size_t)p * NND * EMB;
    const unsigned short* hlo = hlo_all + (size_t)p * NND * EMB;
    const unsigned short* bphi = bphi_all + (size_t)q4 * 16384;
    const unsigned short* bplo = bplo_all + (size_t)q4 * 16384;
    const float* alv = al_all + (size_t)q4 * NH * HD;
    const float* arv = ar_all + (size_t)q4 * NH * HD;
    unsigned short* feat_f16 = feat_all + (size_t)p * NND * EMB;
    float* el = el_all + (size_t)p * NND * NH;
    float* er = er_all + (size_t)p * NND * NH;

    const int lane = threadIdx.x & 63;
    const int wave = threadIdx.x >> 6;
    const int rowbase = blockIdx.x * 32;

    f32x4 acc[2][2];
    #pragma unroll
    for (int m = 0; m < 2; ++m)
        #pragma unroll
        for (int q = 0; q < 2; ++q)
            acc[m][q] = (f32x4){0.f, 0.f, 0.f, 0.f};

    const int ar0 = rowbase + (lane & 15);
    const int ar1 = ar0 + 16;
    const int car0 = ar0 < NND ? ar0 : NND - 1;
    const int car1 = ar1 < NND ? ar1 : NND - 1;
    const int kofs = (lane >> 4) * 8;

    #pragma unroll
    for (int kt = 0; kt < 4; ++kt) {
        const int k0 = kt * 32 + kofs;
        short8v ah0 = *reinterpret_cast<const short8v*>(hhi + (size_t)car0 * EMB + k0);
        short8v av0 = *reinterpret_cast<const short8v*>(hlo + (size_t)car0 * EMB + k0);
        short8v ah1 = *reinterpret_cast<const short8v*>(hhi + (size_t)car1 * EMB + k0);
        short8v av1 = *reinterpret_cast<const short8v*>(hlo + (size_t)car1 * EMB + k0);
        #pragma unroll
        for (int q = 0; q < 2; ++q) {
            const int nn = wave * 2 + q;
            const size_t bofs = ((size_t)(nn * 4 + kt) * 64 + lane) * 8;
            short8v bh = *reinterpret_cast<const short8v*>(bphi + bofs);
            short8v bl = *reinterpret_cast<const short8v*>(bplo + bofs);
            acc[0][q] = __builtin_amdgcn_mfma_f32_16x16x32_bf16(ah0, bh, acc[0][q], 0, 0, 0);
            acc[1][q] = __builtin_amdgcn_mfma_f32_16x16x32_bf16(ah1, bh, acc[1][q], 0, 0, 0);
            acc[0][q] = __builtin_amdgcn_mfma_f32_16x16x32_bf16(av0, bh, acc[0][q], 0, 0, 0);
            acc[1][q] = __builtin_amdgcn_mfma_f32_16x16x32_bf16(av1, bh, acc[1][q], 0, 0, 0);
            acc[0][q] = __builtin_amdgcn_mfma_f32_16x16x32_bf16(ah0, bl, acc[0][q], 0, 0, 0);
            acc[1][q] = __builtin_amdgcn_mfma_f32_16x16x32_bf16(ah1, bl, acc[1][q], 0, 0, 0);
        }
    }
    gemm_epilogue(acc, lane, wave, rowbase, alv, arv, feat_f16, el, er);
}

// ---------------- CSR build: both paths (blockIdx.y = path) ----------------
__global__ __launch_bounds__(256) void bucket_count(
    const int* __restrict__ edges, int* __restrict__ bcnt)
{
    const int p = blockIdx.y;
    const int* dst = edges + (size_t)p * 2 * NE + NE;
    __shared__ int hist[NB];
    const int t = threadIdx.x;
    for (int b = t; b < NB; b += 256) hist[b] = 0;
    __syncthreads();
    const int e0 = blockIdx.x * 2048 + t * 8;
    #pragma unroll
    for (int j = 0; j < 8; ++j) {
        int e = e0 + j;
        if (e < NE) atomicAdd(&hist[dst[e] >> 9], 1);
    }
    __syncthreads();
    for (int b = t; b < NB; b += 256)
        if (hist[b]) atomicAdd(&bcnt[p * 128 + b], hist[b]);
}

__global__ __launch_bounds__(128) void scan_bucket(
    const int* __restrict__ bcnt, int* __restrict__ bbase, int* __restrict__ bcur)
{
    const int p = blockIdx.x;
    __shared__ int s[128];
    const int t = threadIdx.x;
    s[t] = (t < NB) ? bcnt[p * 128 + t] : 0;
    __syncthreads();
    for (int off = 1; off < 128; off <<= 1) {
        int v = (t >= off) ? s[t - off] : 0;
        __syncthreads();
        s[t] += v;
        __syncthreads();
    }
    int excl = (t > 0) ? s[t - 1] : 0;
    if (t <= NB) bbase[p * 128 + t] = excl;
    if (t < NB)  bcur[p * 128 + t]  = excl;
}

__global__ __launch_bounds__(256) void bucket_scatter(
    const int* __restrict__ edges, int* __restrict__ bcur, int* __restrict__ ebuf)
{
    const int p = blockIdx.y;
    const int* src = edges + (size_t)p * 2 * NE;
    const int* dst = src + NE;
    int* eb = ebuf + (size_t)p * NE;
    __shared__ int hist[NB];
    __shared__ int base[NB];
    __shared__ int lcur[NB];
    const int t  = threadIdx.x;
    const int e0 = blockIdx.x * 2048 + t * 8;

    for (int b = t; b < NB; b += 256) { hist[b] = 0; lcur[b] = 0; }
    __syncthreads();

    int sj[8], dj[8];
    bool vj[8];
    #pragma unroll
    for (int j = 0; j < 8; ++j) {
        int e = e0 + j;
        vj[j] = (e < NE);
        if (vj[j]) {
            sj[j] = src[e];
            dj[j] = dst[e];
            atomicAdd(&hist[dj[j] >> 9], 1);
        }
    }
    __syncthreads();
    for (int b = t; b < NB; b += 256) {
        int c = hist[b];
        base[b] = c > 0 ? atomicAdd(&bcur[p * 128 + b], c) : 0;
    }
    __syncthreads();
    #pragma unroll
    for (int j = 0; j < 8; ++j) {
        if (vj[j]) {
            int b   = dj[j] >> 9;
            int off = atomicAdd(&lcur[b], 1);
            eb[(size_t)base[b] + off] = (sj[j] << 9) | (dj[j] & 511);
        }
    }
}

__global__ __launch_bounds__(1024) void bucket_fill(
    const int* __restrict__ bbase, const int* __restrict__ ebuf,
    int* __restrict__ rowptr, int* __restrict__ csrsrc)
{
    const int p = blockIdx.y;
    const int* eb = ebuf + (size_t)p * NE;
    int* rp = rowptr + (size_t)p * (NND + 1);
    int* cs = csrsrc + (size_t)p * NE;
    __shared__ int hist[512];
    __shared__ int excl[512];
    const int b    = blockIdx.x;
    const int n0   = b << 9;
    const int t    = threadIdx.x;
    const int base = bbase[p * 128 + b];
    const int cnt  = bbase[p * 128 + b + 1] - base;

    if (t < 512) hist[t] = 0;
    __syncthreads();
    for (int i = t; i < cnt; i += 1024)
        atomicAdd(&hist[eb[base + i] & 511], 1);
    __syncthreads();
    if (t < 512) excl[t] = hist[t];
    __syncthreads();
    for (int off = 1; off < 512; off <<= 1) {
        int v = 0;
        if (t < 512 && t >= off) v = excl[t - off];
        __syncthreads();
        if (t < 512) excl[t] += v;
        __syncthreads();
    }
    if (t < 512) {
        int e = excl[t] - hist[t];
        int n = n0 + t;
        if (n < NND) rp[n] = base + e;
        hist[t] = e;
    }
    if (b == NB - 1 && t == 0) rp[NND] = NE;
    __syncthreads();
    for (int i = t; i < cnt; i += 1024) {
        int ed = eb[base + i];
        int q = atomicAdd(&hist[ed & 511], 1);
        cs[base + q] = ed >> 9;
    }
}

// ---------------- Gather-aggregate (both paths): one wave per destination node ----------------
// Two-phase chunk with LDS-transposed weights (padded, bank-conflict-free):
//   phase A (lane: edge=lane>>3, head=lane&7): 2 coalesced exps -> wT[wave][head][slot]
//   phase B (lane: dims, head=lane>>3): 4x ds_read_b128 of wT row, 16-deep feat MLP.
__global__ __launch_bounds__(256) void gather_agg(
    const int* __restrict__ rowptr_all, const int* __restrict__ csrsrc_all,
    const float* __restrict__ el_all, const float* __restrict__ er_all,
    const unsigned int* __restrict__ feat_all,
    const float* __restrict__ fs,               // layer0 residual
    const unsigned int* __restrict__ hhi_all,   // l0: out; l1: residual
    const unsigned int* __restrict__ hlo_all,
    const float* __restrict__ bias_all,
    float* __restrict__ esum_all,
    float* __restrict__ out_emb,                // layer1 out
    int layer)
{
    __shared__ float wT[4][NH][WSL];            // [wave][head][slot(16) + pad(4)]
    const int p    = blockIdx.y;
    const int wid  = (blockIdx.x * blockDim.x + threadIdx.x) >> 6;
    const int lane = threadIdx.x & 63;
    const int wave = threadIdx.x >> 6;
    if (wid >= NND) return;
    const int n  = wid;
    const int hB = lane >> 3;   // phase-B head (feat dims)
    const int eA = lane >> 3;   // phase-A edge slot
    const int hA = lane & 7;    // phase-A head

    const int* rowptr = rowptr_all + (size_t)p * (NND + 1);
    const int* csrsrc = csrsrc_all + (size_t)p * NE;
    const float* el   = el_all + (size_t)p * NND * NH;
    const float* er   = er_all + (size_t)p * NND * NH;
    const unsigned int* featu = feat_all + (size_t)p * NND * 64;
    const float* bias = bias_all + (size_t)(p * 2 + layer) * EMB;

    const float ern_a = er[n * NH + hA];
    const int r0 = __builtin_amdgcn_readfirstlane(rowptr[n]);
    const int r1 = __builtin_amdgcn_readfirstlane(rowptr[n + 1]);

    float acc0 = 0.f, acc1 = 0.f, esp = 0.f;
    const float4* wrow = reinterpret_cast<const float4*>(&wT[wave][hB][0]);  // 80B rows, 16B aligned

    int i = r0;
    for (; i + 16 <= r1; i += 16) {
        int sj[16];
        #pragma unroll
        for (int j = 0; j < 16; ++j) sj[j] = csrsrc[i + j];          // uniform
        // phase A: 2 exps per lane, coalesced el rows; transpose via LDS
        float wa = __expf(lrelu(el[sj[eA] * NH + hA] + ern_a));
        float wb = __expf(lrelu(el[sj[eA + 8] * NH + hA] + ern_a));
        esp += wa + wb;
        wT[wave][hA][eA]     = wa;
        wT[wave][hA][eA + 8] = wb;
        // phase B: 16 feat gathers in flight
        unsigned int vs[16];
        #pragma unroll
        for (int j = 0; j < 16; ++j) vs[j] = featu[(size_t)sj[j] * 64 + lane];
        float4 w4[4];
        #pragma unroll
        for (int j = 0; j < 4; ++j) w4[j] = wrow[j];
        const float* wv = reinterpret_cast<const float*>(w4);
        #pragma unroll
        for (int j = 0; j < 16; ++j) {
            __half2 v = *reinterpret_cast<__half2*>(&vs[j]);
            acc0 = fmaf(wv[j], __half2float(__low2half(v)), acc0);
            acc1 = fmaf(wv[j], __half2float(__high2half(v)), acc1);
        }
    }
    if (i < r1) {
        const int m = r1 - i;                              // 1..15, wave-uniform
        int sj[16];
        #pragma unroll
        for (int j = 0; j < 16; ++j) sj[j] = csrsrc[(i + j < r1) ? i + j : r1 - 1];
        float wa = 0.f, wb = 0.f;
        if (eA < m)     wa = __expf(lrelu(el[sj[eA] * NH + hA] + ern_a));
        if (eA + 8 < m) wb = __expf(lrelu(el[sj[eA + 8] * NH + hA] + ern_a));
        esp += wa + wb;
        wT[wave][hA][eA]     = wa;
        wT[wave][hA][eA + 8] = wb;
        float4 w4[4];
        #pragma unroll
        for (int j = 0; j < 4; ++j) w4[j] = wrow[j];
        const float* wv = reinterpret_cast<const float*>(w4);
        #pragma unroll
        for (int j = 0; j < 16; ++j) {
            if (j >= m) break;                             // uniform
            unsigned int vraw = featu[(size_t)sj[j] * 64 + lane];
            __half2 v = *reinterpret_cast<__half2*>(&vraw);
            acc0 = fmaf(wv[j], __half2float(__low2half(v)), acc0);
            acc1 = fmaf(wv[j], __half2float(__high2half(v)), acc1);
        }
    }

    // esum: reduce over the 8 lanes sharing hA (stride-8 lanes)
    esp += __shfl_xor(esp, 8);
    esp += __shfl_xor(esp, 16);
    esp += __shfl_xor(esp, 32);
    if (lane < 8) esum_all[((size_t)p * NND + n) * NH + lane] = esp;
    const float es  = __shfl(esp, hB);                     // total for phase-B head
    const float inv = 1.f / fmaxf(es, 1e-9f);

    float h0, h1;
    if (layer == 0) {
        float2 hv = reinterpret_cast<const float2*>(fs + (size_t)p * NND * EMB)[(size_t)n * 64 + lane];
        h0 = hv.x; h1 = hv.y;
    } else {
        unsigned int hiu = hhi_all[((size_t)p * NND + n) * 64 + lane];
        unsigned int lou = hlo_all[((size_t)p * NND + n) * 64 + lane];
        h0 = __uint_as_float(hiu << 16) + __uint_as_float(lou << 16);
        h1 = __uint_as_float(hiu & 0xffff0000u) + __uint_as_float(lou & 0xffff0000u);
    }
    float o0 = elu(fmaf(acc0, inv, h0 + bias[lane * 2]));
    float o1 = elu(fmaf(acc1, inv, h1 + bias[lane * 2 + 1]));

    if (layer == 1) {
        reinterpret_cast<float2*>(out_emb + (size_t)p * NND * EMB)[(size_t)n * 64 + lane] =
            make_float2(o0, o1);
    } else {
        unsigned short hi0 = f2bf(o0), hi1 = f2bf(o1);
        unsigned short lo0 = f2bf(o0 - bf2f(hi0)), lo1 = f2bf(o1 - bf2f(hi1));
        const size_t idx = ((size_t)p * NND + n) * 64 + lane;
        const_cast<unsigned int*>(hhi_all)[idx] = (unsigned int)hi0 | ((unsigned int)hi1 << 16);
        const_cast<unsigned int*>(hlo_all)[idx] = (unsigned int)lo0 | ((unsigned int)lo1 << 16);
    }
}

// ---------------- alpha (both paths): one thread per edge, all 8 heads ----------------
__global__ __launch_bounds__(256) void alpha_write8(
    const int* __restrict__ edges,
    const float* __restrict__ el_all, const float* __restrict__ er_all,
    const float* __restrict__ esum_all, float* __restrict__ out_alpha)
{
    const int p = blockIdx.y;
    int e = blockIdx.x * 256 + threadIdx.x;
    if (e >= NE) return;
    const int* src = edges + (size_t)p * 2 * NE;
    const int* dst = src + NE;
    const float* el   = el_all   + (size_t)p * NND * NH;
    const float* er   = er_all   + (size_t)p * NND * NH;
    const float* esum = esum_all + (size_t)p * NND * NH;
    int s = src[e], d = dst[e];
    const float4* el4 = reinterpret_cast<const float4*>(el + (size_t)s * 8);
    const float4* er4 = reinterpret_cast<const float4*>(er + (size_t)d * 8);
    const float4* es4 = reinterpret_cast<const float4*>(esum + (size_t)d * 8);
    float4 L0 = el4[0], L1 = el4[1];
    float4 R0 = er4[0], R1 = er4[1];
    float4 S0 = es4[0], S1 = es4[1];
    float4 a0, a1;
    a0.x = __fdividef(__expf(lrelu(L0.x + R0.x)), fmaxf(S0.x, 1e-9f));
    a0.y = __fdividef(__expf(lrelu(L0.y + R0.y)), fmaxf(S0.y, 1e-9f));
    a0.z = __fdividef(__expf(lrelu(L0.z + R0.z)), fmaxf(S0.z, 1e-9f));
    a0.w = __fdividef(__expf(lrelu(L0.w + R0.w)), fmaxf(S0.w, 1e-9f));
    a1.x = __fdividef(__expf(lrelu(L1.x + R1.x)), fmaxf(S1.x, 1e-9f));
    a1.y = __fdividef(__expf(lrelu(L1.y + R1.y)), fmaxf(S1.y, 1e-9f));
    a1.z = __fdividef(__expf(lrelu(L1.z + R1.z)), fmaxf(S1.z, 1e-9f));
    a1.w = __fdividef(__expf(lrelu(L1.w + R1.w)), fmaxf(S1.w, 1e-9f));
    float4* o4 = reinterpret_cast<float4*>(out_alpha + ((size_t)p * NE + e) * 8);
    o4[0] = a0;
    o4[1] = a1;
}

extern "C" void kernel_launch(void* const* d_in, const int* in_sizes, int n_in,
                              void* d_out, int out_size, void* d_ws, size_t ws_size,
                              hipStream_t stream) {
    const float* fs   = (const float*)d_in[0];  // [2][N][128]
    const float* W    = (const float*)d_in[1];  // [2][2][128][128]
    const float* al   = (const float*)d_in[2];  // [2][2][8][16]
    const float* ar   = (const float*)d_in[3];  // [2][2][8][16]
    const float* bias = (const float*)d_in[4];  // [2][2][128]
    const int*   edges= (const int*)d_in[5];    // [2][2][E]

    float* out       = (float*)d_out;
    float* out_emb   = out;                              // [2][N][128]
    float* out_alpha = out + (size_t)2 * NND * EMB;      // [2][E][8]

    char* ws = (char*)d_ws;
    auto take = [&](size_t bytes) {
        char* r = ws;
        ws += (bytes + 15) & ~(size_t)15;
        return r;
    };
    unsigned short* feat_f16 = (unsigned short*)take((size_t)2 * NND * EMB * 2);  // [2][N][128] f16
    unsigned short* hhi      = (unsigned short*)take((size_t)2 * NND * EMB * 2);
    unsigned short* hlo      = (unsigned short*)take((size_t)2 * NND * EMB * 2);  // ebuf aliases here
    float*          el       = (float*)take((size_t)2 * NND * NH * 4);
    float*          er       = (float*)take((size_t)2 * NND * NH * 4);
    float*          esum     = (float*)take((size_t)2 * NND * NH * 4);
    int*            rowptr   = (int*)take((size_t)2 * (NND + 1) * 4);
    int*            bcnt     = (int*)take((size_t)2 * 128 * 4);
    int*            bbase    = (int*)take((size_t)2 * 128 * 4);
    int*            bcur     = (int*)take((size_t)2 * 128 * 4);
    int*            csrsrc   = (int*)take((size_t)2 * NE * 4);
    unsigned short* bphi     = (unsigned short*)take((size_t)4 * 16384 * 2);
    unsigned short* bplo     = (unsigned short*)take((size_t)4 * 16384 * 2);

    int*          ebuf  = (int*)hlo;            // dead until gather l0 writes hlo
    unsigned int* featu = (unsigned int*)feat_f16;
    unsigned int* hhi_u = (unsigned int*)hhi;
    unsigned int* hlo_u = (unsigned int*)hlo;

    // --- CSR build, both paths ---
    hipMemsetAsync(bcnt, 0, (size_t)2 * 128 * 4, stream);
    bucket_count<<<dim3((NE + 2047) / 2048, 2), 256, 0, stream>>>(edges, bcnt);
    scan_bucket<<<2, 128, 0, stream>>>(bcnt, bbase, bcur);
    bucket_scatter<<<dim3((NE + 2047) / 2048, 2), 256, 0, stream>>>(edges, bcur, ebuf);
    bucket_fill<<<dim3(NB, 2), 1024, 0, stream>>>(bbase, ebuf, rowptr, csrsrc);

    // --- weights ---
    wpack4<<<32, 256, 0, stream>>>(W, bphi, bplo);

    // --- layer 0 (both paths per launch) ---
    mfma_gemm_f32<<<dim3((NND + 31) / 32, 2), 256, 0, stream>>>(
        fs, bphi, bplo, al, ar, feat_f16, el, er);
    gather_agg<<<dim3((NND + 3) / 4, 2), 256, 0, stream>>>(
        rowptr, csrsrc, el, er, featu, fs, hhi_u, hlo_u, bias, esum, nullptr, 0);

    // --- layer 1 (both paths per launch) ---
    mfma_gemm_bf<<<dim3((NND + 31) / 32, 2), 256, 0, stream>>>(
        hhi, hlo, bphi, bplo, al, ar, feat_f16, el, er);
    gather_agg<<<dim3((NND + 3) / 4, 2), 256, 0, stream>>>(
        rowptr, csrsrc, el, er, featu, fs, hhi_u, hlo_u, bias, esum, out_emb, 1);
    alpha_write8<<<dim3((NE + 255) / 256, 2), 256, 0, stream>>>(
        edges, el, er, esum, out_alpha);
}

// Round 18
// 567.772 us; speedup vs baseline: 1.1686x; 1.0418x over previous
//
#include <hip/hip_runtime.h>
#include <hip/hip_bf16.h>
#include <hip/hip_fp16.h>

#define NND 50000
#define NE  1600000
#define EMB 128
#define NH  8
#define HD  16
#define NB  98            // ceil(50000/512) buckets of 512 dst nodes
#define WSL 20            // padded slot dim: head rows start at distinct banks

typedef __attribute__((ext_vector_type(8))) short short8v;
typedef __attribute__((ext_vector_type(4))) float f32x4;

__device__ __forceinline__ float lrelu(float x) { return x > 0.f ? x : 0.2f * x; }
__device__ __forceinline__ float elu(float x)   { return x > 0.f ? x : expm1f(x); }

__device__ __forceinline__ unsigned short f2bf(float x) {
    __hip_bfloat16 b = __float2bfloat16(x);
    return *reinterpret_cast<unsigned short*>(&b);
}
__device__ __forceinline__ float bf2f(unsigned short u) {
    __hip_bfloat16 b = *reinterpret_cast<__hip_bfloat16*>(&u);
    return __bfloat162float(b);
}

// ---------------- pack all 4 W matrices into per-fragment bf16 hi/lo ----------------
__global__ __launch_bounds__(256) void wpack4(
    const float* __restrict__ W, unsigned short* __restrict__ bphi, unsigned short* __restrict__ bplo)
{
    int s = blockIdx.x * 256 + threadIdx.x;   // grid 32 x 256 = 8192 = 4*2048
    int q    = s >> 11;
    int sidx = s & 2047;
    int n    = sidx >> 8;
    int kt   = (sidx >> 6) & 3;
    int lane = sidx & 63;
    int col  = n * 16 + (lane & 15);
    int krow = kt * 32 + ((lane >> 4) << 3);
    const float* Wm = W + (size_t)q * EMB * EMB;
    #pragma unroll
    for (int j = 0; j < 8; ++j) {
        float x = Wm[(size_t)(krow + j) * EMB + col];
        unsigned short hi = f2bf(x);
        unsigned short lo = f2bf(x - bf2f(hi));
        bphi[(size_t)s * 8 + j] = hi;
        bplo[(size_t)s * 8 + j] = lo;
    }
}

// ---------------- shared GEMM epilogue (feat f16) ----------------
__device__ __forceinline__ void gemm_epilogue(
    f32x4 acc[2][2], int lane, int wave, int rowbase,
    const float* __restrict__ alv, const float* __restrict__ arv,
    unsigned short* __restrict__ feat_f16, float* __restrict__ el, float* __restrict__ er)
{
    const int colr = lane & 15;
    const int rgrp = lane >> 4;
    #pragma unroll
    for (int m = 0; m < 2; ++m) {
        const int row0 = rowbase + m * 16 + rgrp * 4;
        #pragma unroll
        for (int q = 0; q < 2; ++q) {
            const int nn = wave * 2 + q;
            f32x4 a = acc[m][q];
            #pragma unroll
            for (int r = 0; r < 4; ++r) {
                if (row0 + r < NND)
                    feat_f16[(size_t)(row0 + r) * EMB + nn * 16 + colr] =
                        __half_as_ushort(__float2half(a[r]));
            }
            const float alc = alv[nn * 16 + colr];
            const float arc = arv[nn * 16 + colr];
            float pl[4], pr[4];
            #pragma unroll
            for (int r = 0; r < 4; ++r) { pl[r] = a[r] * alc; pr[r] = a[r] * arc; }
            #pragma unroll
            for (int mask = 1; mask < 16; mask <<= 1) {
                #pragma unroll
                for (int r = 0; r < 4; ++r) {
                    pl[r] += __shfl_xor(pl[r], mask);
                    pr[r] += __shfl_xor(pr[r], mask);
                }
            }
            if (colr == 0) {
                #pragma unroll
                for (int r = 0; r < 4; ++r) {
                    int row = row0 + r;
                    if (row < NND) {
                        el[row * NH + nn] = pl[r];
                        er[row * NH + nn] = pr[r];
                    }
                }
            }
        }
    }
}

// ---------------- MFMA GEMM layer-1 (both paths): A = f32 fs, split in-register ----------------
__global__ __launch_bounds__(256) void mfma_gemm_f32(
    const float* __restrict__ fs,
    const unsigned short* __restrict__ bphi_all, const unsigned short* __restrict__ bplo_all,
    const float* __restrict__ al_all, const float* __restrict__ ar_all,
    unsigned short* __restrict__ feat_all, float* __restrict__ el_all, float* __restrict__ er_all)
{
    const int p = blockIdx.y;
    const int q4 = p * 2;
    const float* hin = fs + (size_t)p * NND * EMB;
    const unsigned short* bphi = bphi_all + (size_t)q4 * 16384;
    const unsigned short* bplo = bplo_all + (size_t)q4 * 16384;
    const float* alv = al_all + (size_t)q4 * NH * HD;
    const float* arv = ar_all + (size_t)q4 * NH * HD;
    unsigned short* feat_f16 = feat_all + (size_t)p * NND * EMB;
    float* el = el_all + (size_t)p * NND * NH;
    float* er = er_all + (size_t)p * NND * NH;

    const int lane = threadIdx.x & 63;
    const int wave = threadIdx.x >> 6;
    const int rowbase = blockIdx.x * 32;

    f32x4 acc[2][2];
    #pragma unroll
    for (int m = 0; m < 2; ++m)
        #pragma unroll
        for (int q = 0; q < 2; ++q)
            acc[m][q] = (f32x4){0.f, 0.f, 0.f, 0.f};

    const int ar0 = rowbase + (lane & 15);
    const int ar1 = ar0 + 16;
    const int car0 = ar0 < NND ? ar0 : NND - 1;
    const int car1 = ar1 < NND ? ar1 : NND - 1;
    const int kofs = (lane >> 4) * 8;

    #pragma unroll
    for (int kt = 0; kt < 4; ++kt) {
        const int k0 = kt * 32 + kofs;
        short8v ah0, av0, ah1, av1;
        {
            const float4* fr = reinterpret_cast<const float4*>(hin + (size_t)car0 * EMB + k0);
            float4 x0 = fr[0], x1 = fr[1];
            float xs[8] = { x0.x, x0.y, x0.z, x0.w, x1.x, x1.y, x1.z, x1.w };
            #pragma unroll
            for (int j = 0; j < 8; ++j) {
                unsigned short hi = f2bf(xs[j]);
                ah0[j] = (short)hi;
                av0[j] = (short)f2bf(xs[j] - bf2f(hi));
            }
        }
        {
            const float4* fr = reinterpret_cast<const float4*>(hin + (size_t)car1 * EMB + k0);
            float4 x0 = fr[0], x1 = fr[1];
            float xs[8] = { x0.x, x0.y, x0.z, x0.w, x1.x, x1.y, x1.z, x1.w };
            #pragma unroll
            for (int j = 0; j < 8; ++j) {
                unsigned short hi = f2bf(xs[j]);
                ah1[j] = (short)hi;
                av1[j] = (short)f2bf(xs[j] - bf2f(hi));
            }
        }
        #pragma unroll
        for (int q = 0; q < 2; ++q) {
            const int nn = wave * 2 + q;
            const size_t bofs = ((size_t)(nn * 4 + kt) * 64 + lane) * 8;
            short8v bh = *reinterpret_cast<const short8v*>(bphi + bofs);
            short8v bl = *reinterpret_cast<const short8v*>(bplo + bofs);
            acc[0][q] = __builtin_amdgcn_mfma_f32_16x16x32_bf16(ah0, bh, acc[0][q], 0, 0, 0);
            acc[1][q] = __builtin_amdgcn_mfma_f32_16x16x32_bf16(ah1, bh, acc[1][q], 0, 0, 0);
            acc[0][q] = __builtin_amdgcn_mfma_f32_16x16x32_bf16(av0, bh, acc[0][q], 0, 0, 0);
            acc[1][q] = __builtin_amdgcn_mfma_f32_16x16x32_bf16(av1, bh, acc[1][q], 0, 0, 0);
            acc[0][q] = __builtin_amdgcn_mfma_f32_16x16x32_bf16(ah0, bl, acc[0][q], 0, 0, 0);
            acc[1][q] = __builtin_amdgcn_mfma_f32_16x16x32_bf16(ah1, bl, acc[1][q], 0, 0, 0);
        }
    }
    gemm_epilogue(acc, lane, wave, rowbase, alv, arv, feat_f16, el, er);
}

// ---------------- MFMA GEMM layer-2 (both paths): A = bf16 hi/lo ----------------
__global__ __launch_bounds__(256) void mfma_gemm_bf(
    const unsigned short* __restrict__ hhi_all, const unsigned short* __restrict__ hlo_all,
    const unsigned short* __restrict__ bphi_all, const unsigned short* __restrict__ bplo_all,
    const float* __restrict__ al_all, const float* __restrict__ ar_all,
    unsigned short* __restrict__ feat_all, float* __restrict__ el_all, float* __restrict__ er_all)
{
    const int p = blockIdx.y;
    const int q4 = p * 2 + 1;
    const unsigned short* hhi = hhi_all + (size_t)p * NND * EMB;
    const unsigned short* hlo = hlo_all + (size_t)p * NND * EMB;
    const unsigned short* bphi = bphi_all + (size_t)q4 * 16384;
    const unsigned short* bplo = bplo_all + (size_t)q4 * 16384;
    const float* alv = al_all + (size_t)q4 * NH * HD;
    const float* arv = ar_all + (size_t)q4 * NH * HD;
    unsigned short* feat_f16 = feat_all + (size_t)p * NND * EMB;
    float* el = el_all + (size_t)p * NND * NH;
    float* er = er_all + (size_t)p * NND * NH;

    const int lane = threadIdx.x & 63;
    const int wave = threadIdx.x >> 6;
    const int rowbase = blockIdx.x * 32;

    f32x4 acc[2][2];
    #pragma unroll
    for (int m = 0; m < 2; ++m)
        #pragma unroll
        for (int q = 0; q < 2; ++q)
            acc[m][q] = (f32x4){0.f, 0.f, 0.f, 0.f};

    const int ar0 = rowbase + (lane & 15);
    const int ar1 = ar0 + 16;
    const int car0 = ar0 < NND ? ar0 : NND - 1;
    const int car1 = ar1 < NND ? ar1 : NND - 1;
    const int kofs = (lane >> 4) * 8;

    #pragma unroll
    for (int kt = 0; kt < 4; ++kt) {
        const int k0 = kt * 32 + kofs;
        short8v ah0 = *reinterpret_cast<const short8v*>(hhi + (size_t)car0 * EMB + k0);
        short8v av0 = *reinterpret_cast<const short8v*>(hlo + (size_t)car0 * EMB + k0);
        short8v ah1 = *reinterpret_cast<const short8v*>(hhi + (size_t)car1 * EMB + k0);
        short8v av1 = *reinterpret_cast<const short8v*>(hlo + (size_t)car1 * EMB + k0);
        #pragma unroll
        for (int q = 0; q < 2; ++q) {
            const int nn = wave * 2 + q;
            const size_t bofs = ((size_t)(nn * 4 + kt) * 64 + lane) * 8;
            short8v bh = *reinterpret_cast<const short8v*>(bphi + bofs);
            short8v bl = *reinterpret_cast<const short8v*>(bplo + bofs);
            acc[0][q] = __builtin_amdgcn_mfma_f32_16x16x32_bf16(ah0, bh, acc[0][q], 0, 0, 0);
            acc[1][q] = __builtin_amdgcn_mfma_f32_16x16x32_bf16(ah1, bh, acc[1][q], 0, 0, 0);
            acc[0][q] = __builtin_amdgcn_mfma_f32_16x16x32_bf16(av0, bh, acc[0][q], 0, 0, 0);
            acc[1][q] = __builtin_amdgcn_mfma_f32_16x16x32_bf16(av1, bh, acc[1][q], 0, 0, 0);
            acc[0][q] = __builtin_amdgcn_mfma_f32_16x16x32_bf16(ah0, bl, acc[0][q], 0, 0, 0);
            acc[1][q] = __builtin_amdgcn_mfma_f32_16x16x32_bf16(ah1, bl, acc[1][q], 0, 0, 0);
        }
    }
    gemm_epilogue(acc, lane, wave, rowbase, alv, arv, feat_f16, el, er);
}

// ---------------- CSR build: both paths (blockIdx.y = path) ----------------
__global__ __launch_bounds__(256) void bucket_count(
    const int* __restrict__ edges, int* __restrict__ bcnt)
{
    const int p = blockIdx.y;
    const int* dst = edges + (size_t)p * 2 * NE + NE;
    __shared__ int hist[NB];
    const int t = threadIdx.x;
    for (int b = t; b < NB; b += 256) hist[b] = 0;
    __syncthreads();
    const int e0 = blockIdx.x * 2048 + t * 8;
    #pragma unroll
    for (int j = 0; j < 8; ++j) {
        int e = e0 + j;
        if (e < NE) atomicAdd(&hist[dst[e] >> 9], 1);
    }
    __syncthreads();
    for (int b = t; b < NB; b += 256)
        if (hist[b]) atomicAdd(&bcnt[p * 128 + b], hist[b]);
}

__global__ __launch_bounds__(128) void scan_bucket(
    const int* __restrict__ bcnt, int* __restrict__ bbase, int* __restrict__ bcur)
{
    const int p = blockIdx.x;
    __shared__ int s[128];
    const int t = threadIdx.x;
    s[t] = (t < NB) ? bcnt[p * 128 + t] : 0;
    __syncthreads();
    for (int off = 1; off < 128; off <<= 1) {
        int v = (t >= off) ? s[t - off] : 0;
        __syncthreads();
        s[t] += v;
        __syncthreads();
    }
    int excl = (t > 0) ? s[t - 1] : 0;
    if (t <= NB) bbase[p * 128 + t] = excl;
    if (t < NB)  bcur[p * 128 + t]  = excl;
}

__global__ __launch_bounds__(256) void bucket_scatter(
    const int* __restrict__ edges, int* __restrict__ bcur, int* __restrict__ ebuf)
{
    const int p = blockIdx.y;
    const int* src = edges + (size_t)p * 2 * NE;
    const int* dst = src + NE;
    int* eb = ebuf + (size_t)p * NE;
    __shared__ int hist[NB];
    __shared__ int base[NB];
    __shared__ int lcur[NB];
    const int t  = threadIdx.x;
    const int e0 = blockIdx.x * 2048 + t * 8;

    for (int b = t; b < NB; b += 256) { hist[b] = 0; lcur[b] = 0; }
    __syncthreads();

    int sj[8], dj[8];
    bool vj[8];
    #pragma unroll
    for (int j = 0; j < 8; ++j) {
        int e = e0 + j;
        vj[j] = (e < NE);
        if (vj[j]) {
            sj[j] = src[e];
            dj[j] = dst[e];
            atomicAdd(&hist[dj[j] >> 9], 1);
        }
    }
    __syncthreads();
    for (int b = t; b < NB; b += 256) {
        int c = hist[b];
        base[b] = c > 0 ? atomicAdd(&bcur[p * 128 + b], c) : 0;
    }
    __syncthreads();
    #pragma unroll
    for (int j = 0; j < 8; ++j) {
        if (vj[j]) {
            int b   = dj[j] >> 9;
            int off = atomicAdd(&lcur[b], 1);
            eb[(size_t)base[b] + off] = (sj[j] << 9) | (dj[j] & 511);
        }
    }
}

__global__ __launch_bounds__(1024) void bucket_fill(
    const int* __restrict__ bbase, const int* __restrict__ ebuf,
    int* __restrict__ rowptr, int* __restrict__ csrsrc)
{
    const int p = blockIdx.y;
    const int* eb = ebuf + (size_t)p * NE;
    int* rp = rowptr + (size_t)p * (NND + 1);
    int* cs = csrsrc + (size_t)p * NE;
    __shared__ int hist[512];
    __shared__ int excl[512];
    const int b    = blockIdx.x;
    const int n0   = b << 9;
    const int t    = threadIdx.x;
    const int base = bbase[p * 128 + b];
    const int cnt  = bbase[p * 128 + b + 1] - base;

    if (t < 512) hist[t] = 0;
    __syncthreads();
    for (int i = t; i < cnt; i += 1024)
        atomicAdd(&hist[eb[base + i] & 511], 1);
    __syncthreads();
    if (t < 512) excl[t] = hist[t];
    __syncthreads();
    for (int off = 1; off < 512; off <<= 1) {
        int v = 0;
        if (t < 512 && t >= off) v = excl[t - off];
        __syncthreads();
        if (t < 512) excl[t] += v;
        __syncthreads();
    }
    if (t < 512) {
        int e = excl[t] - hist[t];
        int n = n0 + t;
        if (n < NND) rp[n] = base + e;
        hist[t] = e;
    }
    if (b == NB - 1 && t == 0) rp[NND] = NE;
    __syncthreads();
    for (int i = t; i < cnt; i += 1024) {
        int ed = eb[base + i];
        int q = atomicAdd(&hist[ed & 511], 1);
        cs[base + q] = ed >> 9;
    }
}

// ---------------- Gather-aggregate (both paths): one wave per destination node ----------------
// Two-phase chunk, NO local arrays / NO dynamic indexing (defeats PromoteAlloca->LDS):
//   phase A (lane: edge=lane>>3, head=lane&7): 2 coalesced exps -> wT[wave][head][slot]
//   phase B (lane: dims, head=lane>>3): named float4 reads of wT row, 16 named gathers.
#define FMA2(W, V) do { \
    __half2 _hv = *reinterpret_cast<const __half2*>(&(V)); \
    acc0 = fmaf((W), __half2float(__low2half(_hv)), acc0); \
    acc1 = fmaf((W), __half2float(__high2half(_hv)), acc1); } while (0)

__global__ __launch_bounds__(256) void gather_agg(
    const int* __restrict__ rowptr_all, const int* __restrict__ csrsrc_all,
    const float* __restrict__ el_all, const float* __restrict__ er_all,
    const unsigned int* __restrict__ feat_all,
    const float* __restrict__ fs,               // layer0 residual
    const unsigned int* __restrict__ hhi_all,   // l0: out; l1: residual
    const unsigned int* __restrict__ hlo_all,
    const float* __restrict__ bias_all,
    float* __restrict__ esum_all,
    float* __restrict__ out_emb,                // layer1 out
    int layer)
{
    __shared__ float wT[4][NH][WSL];            // [wave][head][slot(16) + pad]
    const int p    = blockIdx.y;
    const int wid  = (blockIdx.x * blockDim.x + threadIdx.x) >> 6;
    const int lane = threadIdx.x & 63;
    const int wave = threadIdx.x >> 6;
    if (wid >= NND) return;
    const int n  = wid;
    const int hB = lane >> 3;   // phase-B head (feat dims)
    const int eA = lane >> 3;   // phase-A edge slot
    const int hA = lane & 7;    // phase-A head

    const int* rowptr = rowptr_all + (size_t)p * (NND + 1);
    const int* csrsrc = csrsrc_all + (size_t)p * NE;
    const float* el   = el_all + (size_t)p * NND * NH;
    const float* er   = er_all + (size_t)p * NND * NH;
    const unsigned int* featu = feat_all + (size_t)p * NND * 64;
    const float* bias = bias_all + (size_t)(p * 2 + layer) * EMB;

    const float ern_a = er[n * NH + hA];
    const int r0 = __builtin_amdgcn_readfirstlane(rowptr[n]);
    const int r1 = __builtin_amdgcn_readfirstlane(rowptr[n + 1]);

    float acc0 = 0.f, acc1 = 0.f, esp = 0.f;
    const float4* wrow = reinterpret_cast<const float4*>(&wT[wave][hB][0]);

    const int nfull = r0 + ((r1 - r0) & ~15);
    int i = r0;
    for (; i < nfull; i += 16) {
        int s0 = csrsrc[i +  0], s1 = csrsrc[i +  1], s2  = csrsrc[i +  2], s3  = csrsrc[i +  3],
            s4 = csrsrc[i +  4], s5 = csrsrc[i +  5], s6  = csrsrc[i +  6], s7  = csrsrc[i +  7],
            s8 = csrsrc[i +  8], s9 = csrsrc[i +  9], s10 = csrsrc[i + 10], s11 = csrsrc[i + 11],
            s12= csrsrc[i + 12], s13= csrsrc[i + 13], s14 = csrsrc[i + 14], s15 = csrsrc[i + 15];
        int sA0 = csrsrc[i + eA], sA1 = csrsrc[i + eA + 8];
        float wa = __expf(lrelu(el[sA0 * NH + hA] + ern_a));
        float wb = __expf(lrelu(el[sA1 * NH + hA] + ern_a));
        esp += wa + wb;
        wT[wave][hA][eA]     = wa;
        wT[wave][hA][eA + 8] = wb;
        unsigned int v0  = featu[(size_t)s0  * 64 + lane], v1  = featu[(size_t)s1  * 64 + lane],
                     v2  = featu[(size_t)s2  * 64 + lane], v3  = featu[(size_t)s3  * 64 + lane],
                     v4  = featu[(size_t)s4  * 64 + lane], v5  = featu[(size_t)s5  * 64 + lane],
                     v6  = featu[(size_t)s6  * 64 + lane], v7  = featu[(size_t)s7  * 64 + lane],
                     v8  = featu[(size_t)s8  * 64 + lane], v9  = featu[(size_t)s9  * 64 + lane],
                     v10 = featu[(size_t)s10 * 64 + lane], v11 = featu[(size_t)s11 * 64 + lane],
                     v12 = featu[(size_t)s12 * 64 + lane], v13 = featu[(size_t)s13 * 64 + lane],
                     v14 = featu[(size_t)s14 * 64 + lane], v15 = featu[(size_t)s15 * 64 + lane];
        float4 wq0 = wrow[0], wq1 = wrow[1], wq2 = wrow[2], wq3 = wrow[3];
        FMA2(wq0.x, v0);  FMA2(wq0.y, v1);  FMA2(wq0.z, v2);  FMA2(wq0.w, v3);
        FMA2(wq1.x, v4);  FMA2(wq1.y, v5);  FMA2(wq1.z, v6);  FMA2(wq1.w, v7);
        FMA2(wq2.x, v8);  FMA2(wq2.y, v9);  FMA2(wq2.z, v10); FMA2(wq2.w, v11);
        FMA2(wq3.x, v12); FMA2(wq3.y, v13); FMA2(wq3.z, v14); FMA2(wq3.w, v15);
    }
    if (i < r1) {
        const int m   = r1 - i;                 // 1..15, wave-uniform
        const int lim = r1 - 1;
        #define CLI(J) csrsrc[(i + (J) < r1) ? i + (J) : lim]
        int s0 = CLI(0),  s1 = CLI(1),  s2  = CLI(2),  s3  = CLI(3),
            s4 = CLI(4),  s5 = CLI(5),  s6  = CLI(6),  s7  = CLI(7),
            s8 = CLI(8),  s9 = CLI(9),  s10 = CLI(10), s11 = CLI(11),
            s12= CLI(12), s13= CLI(13), s14 = CLI(14), s15 = CLI(15);
        int sA0 = CLI(eA), sA1 = CLI(eA + 8);
        #undef CLI
        float wa = (eA < m)     ? __expf(lrelu(el[sA0 * NH + hA] + ern_a)) : 0.f;
        float wb = (eA + 8 < m) ? __expf(lrelu(el[sA1 * NH + hA] + ern_a)) : 0.f;
        esp += wa + wb;
        wT[wave][hA][eA]     = wa;
        wT[wave][hA][eA + 8] = wb;
        unsigned int v0  = featu[(size_t)s0  * 64 + lane], v1  = featu[(size_t)s1  * 64 + lane],
                     v2  = featu[(size_t)s2  * 64 + lane], v3  = featu[(size_t)s3  * 64 + lane],
                     v4  = featu[(size_t)s4  * 64 + lane], v5  = featu[(size_t)s5  * 64 + lane],
                     v6  = featu[(size_t)s6  * 64 + lane], v7  = featu[(size_t)s7  * 64 + lane],
                     v8  = featu[(size_t)s8  * 64 + lane], v9  = featu[(size_t)s9  * 64 + lane],
                     v10 = featu[(size_t)s10 * 64 + lane], v11 = featu[(size_t)s11 * 64 + lane],
                     v12 = featu[(size_t)s12 * 64 + lane], v13 = featu[(size_t)s13 * 64 + lane],
                     v14 = featu[(size_t)s14 * 64 + lane], v15 = featu[(size_t)s15 * 64 + lane];
        float4 wq0 = wrow[0], wq1 = wrow[1], wq2 = wrow[2], wq3 = wrow[3];
        FMA2(wq0.x, v0);  FMA2(wq0.y, v1);  FMA2(wq0.z, v2);  FMA2(wq0.w, v3);
        FMA2(wq1.x, v4);  FMA2(wq1.y, v5);  FMA2(wq1.z, v6);  FMA2(wq1.w, v7);
        FMA2(wq2.x, v8);  FMA2(wq2.y, v9);  FMA2(wq2.z, v10); FMA2(wq2.w, v11);
        FMA2(wq3.x, v12); FMA2(wq3.y, v13); FMA2(wq3.z, v14); FMA2(wq3.w, v15);
    }

    // esum: reduce over the 8 lanes sharing hA (stride-8 lanes)
    esp += __shfl_xor(esp, 8);
    esp += __shfl_xor(esp, 16);
    esp += __shfl_xor(esp, 32);
    if (lane < 8) esum_all[((size_t)p * NND + n) * NH + lane] = esp;
    const float es  = __shfl(esp, hB);          // total for phase-B head
    const float inv = 1.f / fmaxf(es, 1e-9f);

    float h0, h1;
    if (layer == 0) {
        float2 hv = reinterpret_cast<const float2*>(fs + (size_t)p * NND * EMB)[(size_t)n * 64 + lane];
        h0 = hv.x; h1 = hv.y;
    } else {
        unsigned int hiu = hhi_all[((size_t)p * NND + n) * 64 + lane];
        unsigned int lou = hlo_all[((size_t)p * NND + n) * 64 + lane];
        h0 = __uint_as_float(hiu << 16) + __uint_as_float(lou << 16);
        h1 = __uint_as_float(hiu & 0xffff0000u) + __uint_as_float(lou & 0xffff0000u);
    }
    float o0 = elu(fmaf(acc0, inv, h0 + bias[lane * 2]));
    float o1 = elu(fmaf(acc1, inv, h1 + bias[lane * 2 + 1]));

    if (layer == 1) {
        reinterpret_cast<float2*>(out_emb + (size_t)p * NND * EMB)[(size_t)n * 64 + lane] =
            make_float2(o0, o1);
    } else {
        unsigned short hi0 = f2bf(o0), hi1 = f2bf(o1);
        unsigned short lo0 = f2bf(o0 - bf2f(hi0)), lo1 = f2bf(o1 - bf2f(hi1));
        const size_t idx = ((size_t)p * NND + n) * 64 + lane;
        const_cast<unsigned int*>(hhi_all)[idx] = (unsigned int)hi0 | ((unsigned int)hi1 << 16);
        const_cast<unsigned int*>(hlo_all)[idx] = (unsigned int)lo0 | ((unsigned int)lo1 << 16);
    }
}

// ---------------- alpha (both paths): one thread per edge, all 8 heads ----------------
__global__ __launch_bounds__(256) void alpha_write8(
    const int* __restrict__ edges,
    const float* __restrict__ el_all, const float* __restrict__ er_all,
    const float* __restrict__ esum_all, float* __restrict__ out_alpha)
{
    const int p = blockIdx.y;
    int e = blockIdx.x * 256 + threadIdx.x;
    if (e >= NE) return;
    const int* src = edges + (size_t)p * 2 * NE;
    const int* dst = src + NE;
    const float* el   = el_all   + (size_t)p * NND * NH;
    const float* er   = er_all   + (size_t)p * NND * NH;
    const float* esum = esum_all + (size_t)p * NND * NH;
    int s = src[e], d = dst[e];
    const float4* el4 = reinterpret_cast<const float4*>(el + (size_t)s * 8);
    const float4* er4 = reinterpret_cast<const float4*>(er + (size_t)d * 8);
    const float4* es4 = reinterpret_cast<const float4*>(esum + (size_t)d * 8);
    float4 L0 = el4[0], L1 = el4[1];
    float4 R0 = er4[0], R1 = er4[1];
    float4 S0 = es4[0], S1 = es4[1];
    float4 a0, a1;
    a0.x = __fdividef(__expf(lrelu(L0.x + R0.x)), fmaxf(S0.x, 1e-9f));
    a0.y = __fdividef(__expf(lrelu(L0.y + R0.y)), fmaxf(S0.y, 1e-9f));
    a0.z = __fdividef(__expf(lrelu(L0.z + R0.z)), fmaxf(S0.z, 1e-9f));
    a0.w = __fdividef(__expf(lrelu(L0.w + R0.w)), fmaxf(S0.w, 1e-9f));
    a1.x = __fdividef(__expf(lrelu(L1.x + R1.x)), fmaxf(S1.x, 1e-9f));
    a1.y = __fdividef(__expf(lrelu(L1.y + R1.y)), fmaxf(S1.y, 1e-9f));
    a1.z = __fdividef(__expf(lrelu(L1.z + R1.z)), fmaxf(S1.z, 1e-9f));
    a1.w = __fdividef(__expf(lrelu(L1.w + R1.w)), fmaxf(S1.w, 1e-9f));
    float4* o4 = reinterpret_cast<float4*>(out_alpha + ((size_t)p * NE + e) * 8);
    o4[0] = a0;
    o4[1] = a1;
}

extern "C" void kernel_launch(void* const* d_in, const int* in_sizes, int n_in,
                              void* d_out, int out_size, void* d_ws, size_t ws_size,
                              hipStream_t stream) {
    const float* fs   = (const float*)d_in[0];  // [2][N][128]
    const float* W    = (const float*)d_in[1];  // [2][2][128][128]
    const float* al   = (const float*)d_in[2];  // [2][2][8][16]
    const float* ar   = (const float*)d_in[3];  // [2][2][8][16]
    const float* bias = (const float*)d_in[4];  // [2][2][128]
    const int*   edges= (const int*)d_in[5];    // [2][2][E]

    float* out       = (float*)d_out;
    float* out_emb   = out;                              // [2][N][128]
    float* out_alpha = out + (size_t)2 * NND * EMB;      // [2][E][8]

    char* ws = (char*)d_ws;
    auto take = [&](size_t bytes) {
        char* r = ws;
        ws += (bytes + 15) & ~(size_t)15;
        return r;
    };
    unsigned short* feat_f16 = (unsigned short*)take((size_t)2 * NND * EMB * 2);  // [2][N][128] f16
    unsigned short* hhi      = (unsigned short*)take((size_t)2 * NND * EMB * 2);
    unsigned short* hlo      = (unsigned short*)take((size_t)2 * NND * EMB * 2);  // ebuf aliases here
    float*          el       = (float*)take((size_t)2 * NND * NH * 4);
    float*          er       = (float*)take((size_t)2 * NND * NH * 4);
    float*          esum     = (float*)take((size_t)2 * NND * NH * 4);
    int*            rowptr   = (int*)take((size_t)2 * (NND + 1) * 4);
    int*            bcnt     = (int*)take((size_t)2 * 128 * 4);
    int*            bbase    = (int*)take((size_t)2 * 128 * 4);
    int*            bcur     = (int*)take((size_t)2 * 128 * 4);
    int*            csrsrc   = (int*)take((size_t)2 * NE * 4);
    unsigned short* bphi     = (unsigned short*)take((size_t)4 * 16384 * 2);
    unsigned short* bplo     = (unsigned short*)take((size_t)4 * 16384 * 2);

    int*          ebuf  = (int*)hlo;            // dead until gather l0 writes hlo
    unsigned int* featu = (unsigned int*)feat_f16;
    unsigned int* hhi_u = (unsigned int*)hhi;
    unsigned int* hlo_u = (unsigned int*)hlo;

    // --- CSR build, both paths ---
    hipMemsetAsync(bcnt, 0, (size_t)2 * 128 * 4, stream);
    bucket_count<<<dim3((NE + 2047) / 2048, 2), 256, 0, stream>>>(edges, bcnt);
    scan_bucket<<<2, 128, 0, stream>>>(bcnt, bbase, bcur);
    bucket_scatter<<<dim3((NE + 2047) / 2048, 2), 256, 0, stream>>>(edges, bcur, ebuf);
    bucket_fill<<<dim3(NB, 2), 1024, 0, stream>>>(bbase, ebuf, rowptr, csrsrc);

    // --- weights ---
    wpack4<<<32, 256, 0, stream>>>(W, bphi, bplo);

    // --- layer 0 (both paths per launch) ---
    mfma_gemm_f32<<<dim3((NND + 31) / 32, 2), 256, 0, stream>>>(
        fs, bphi, bplo, al, ar, feat_f16, el, er);
    gather_agg<<<dim3((NND + 3) / 4, 2), 256, 0, stream>>>(
        rowptr, csrsrc, el, er, featu, fs, hhi_u, hlo_u, bias, esum, nullptr, 0);

    // --- layer 1 (both paths per launch) ---
    mfma_gemm_bf<<<dim3((NND + 31) / 32, 2), 256, 0, stream>>>(
        hhi, hlo, bphi, bplo, al, ar, feat_f16, el, er);
    gather_agg<<<dim3((NND + 3) / 4, 2), 256, 0, stream>>>(
        rowptr, csrsrc, el, er, featu, fs, hhi_u, hlo_u, bias, esum, out_emb, 1);
    alpha_write8<<<dim3((NE + 255) / 256, 2), 256, 0, stream>>>(
        edges, el, er, esum, out_alpha);
}